// Round 5
// baseline (884.657 us; speedup 1.0000x reference)
//
#include <hip/hip_runtime.h>

#define N_NODES 100000
#define N_EDGES 1600000
#define F_IN 17
#define H 128
#define K_TYPES 6
#define MD 12
#define OUT_F 150
#define EPSL 1e-5f

#define SCAN_BLOCKS 391  // ceil(100000/256)

#define LDH 136  // LDS row stride (bf16) for 128-col tiles
#define LDZ 72   // LDS row stride (bf16) for 64-col tiles

typedef __attribute__((ext_vector_type(8))) short bf16x8;
typedef __attribute__((ext_vector_type(4))) float f32x4;
typedef __attribute__((ext_vector_type(4))) short s16x4;

static __device__ __forceinline__ short f2bf(float f) {
    union { float f; unsigned u; } v;
    v.f = f;
    unsigned r = (v.u + 0x7FFF + ((v.u >> 16) & 1)) >> 16;  // RNE
    return (short)r;
}

// unpack int4 = 8 bf16 and accumulate into acc[0..7]
static __device__ __forceinline__ void acc8(float* a, int4 u) {
    union { unsigned u; float f; } lo, hi;
    lo.u = ((unsigned)u.x) << 16; hi.u = ((unsigned)u.x) & 0xFFFF0000u; a[0] += lo.f; a[1] += hi.f;
    lo.u = ((unsigned)u.y) << 16; hi.u = ((unsigned)u.y) & 0xFFFF0000u; a[2] += lo.f; a[3] += hi.f;
    lo.u = ((unsigned)u.z) << 16; hi.u = ((unsigned)u.z) & 0xFFFF0000u; a[4] += lo.f; a[5] += hi.f;
    lo.u = ((unsigned)u.w) << 16; hi.u = ((unsigned)u.w) & 0xFFFF0000u; a[6] += lo.f; a[7] += hi.f;
}

// ---------- CSR build: histogram ----------
__global__ __launch_bounds__(256) void k_hist(const int* __restrict__ ei,
                                              int* __restrict__ cnt) {
    int e = blockIdx.x * 256 + threadIdx.x;
    int dst = ei[N_EDGES + e];
    atomicAdd(&cnt[dst], 1);
}

// ---------- CSR build: scan stage 1 ----------
__global__ __launch_bounds__(256) void k_scan1(const int* __restrict__ cnt,
                                               int* __restrict__ rowstart,
                                               int* __restrict__ blocksums) {
    __shared__ int s[256];
    int tid = threadIdx.x;
    int i = blockIdx.x * 256 + tid;
    int v = (i < N_NODES) ? cnt[i] : 0;
    s[tid] = v;
    __syncthreads();
    for (int off = 1; off < 256; off <<= 1) {
        int t = (tid >= off) ? s[tid - off] : 0;
        __syncthreads();
        s[tid] += t;
        __syncthreads();
    }
    if (i < N_NODES) rowstart[i] = s[tid] - v;
    if (tid == 255) blocksums[blockIdx.x] = s[255];
}

// ---------- CSR build: scan stage 2 ----------
__global__ __launch_bounds__(512) void k_scan2(int* __restrict__ blocksums) {
    __shared__ int s[512];
    int t = threadIdx.x;
    int v0 = (t < SCAN_BLOCKS) ? blocksums[t] : 0;
    s[t] = v0;
    __syncthreads();
    for (int off = 1; off < 512; off <<= 1) {
        int tv = (t >= off) ? s[t - off] : 0;
        __syncthreads();
        s[t] += tv;
        __syncthreads();
    }
    if (t < SCAN_BLOCKS) blocksums[t] = s[t] - v0;
}

// ---------- CSR build: scan stage 3 ----------
__global__ __launch_bounds__(256) void k_scan3(int* __restrict__ rowstart,
                                               const int* __restrict__ blocksums,
                                               int* __restrict__ cursor) {
    int i = blockIdx.x * 256 + threadIdx.x;
    if (i < N_NODES) {
        int r = rowstart[i] + blocksums[blockIdx.x];
        rowstart[i] = r;
        cursor[i] = r;
    }
}

// ---------- CSR build: fill ----------
__global__ __launch_bounds__(256) void k_fill(const int* __restrict__ ei,
                                              int* __restrict__ cursor,
                                              int* __restrict__ sorted_src) {
    int e = blockIdx.x * 256 + threadIdx.x;
    int src = ei[e];
    int dst = ei[N_EDGES + e];
    int pos = atomicAdd(&cursor[dst], 1);
    sorted_src[pos] = src;
}

// ---------- degree sort: histogram over clamped degree ----------
__global__ __launch_bounds__(256) void k_deghist(const int* __restrict__ cnt,
                                                 int* __restrict__ dbins) {
    __shared__ int lb[64];
    int t = threadIdx.x;
    if (t < 64) lb[t] = 0;
    __syncthreads();
    int i = blockIdx.x * 256 + t;
    if (i < N_NODES) {
        int d = cnt[i]; if (d > 63) d = 63;
        atomicAdd(&lb[d], 1);
    }
    __syncthreads();
    if (t < 64 && lb[t] > 0) atomicAdd(&dbins[t], lb[t]);
}

// ---------- degree sort: exclusive scan of 64 bins ----------
__global__ __launch_bounds__(64) void k_degscan(const int* __restrict__ dbins,
                                                int* __restrict__ dcur) {
    __shared__ int s[64];
    int t = threadIdx.x;
    int v = dbins[t];
    s[t] = v;
    __syncthreads();
    for (int off = 1; off < 64; off <<= 1) {
        int tv = (t >= off) ? s[t - off] : 0;
        __syncthreads();
        s[t] += tv;
        __syncthreads();
    }
    dcur[t] = s[t] - v;
}

// ---------- degree sort: scatter node ids by degree ----------
__global__ __launch_bounds__(256) void k_degscatter(const int* __restrict__ cnt,
                                                    int* __restrict__ dcur,
                                                    int* __restrict__ perm) {
    int i = blockIdx.x * 256 + threadIdx.x;
    if (i < N_NODES) {
        int d = cnt[i]; if (d > 63) d = 63;
        int pos = atomicAdd(&dcur[d], 1);
        perm[pos] = i;
    }
}

// ---------- prep: BN-fold + transpose + bf16-convert head weights ----------
__global__ __launch_bounds__(256) void k_prep(
    const float* __restrict__ ch_W1, const float* __restrict__ ch_W2,
    const float* __restrict__ ch_W3,
    const float* __restrict__ c1g, const float* __restrict__ c1b,
    const float* __restrict__ c1m, const float* __restrict__ c1v,
    const float* __restrict__ c2g, const float* __restrict__ c2b,
    const float* __restrict__ c2m, const float* __restrict__ c2v,
    const float* __restrict__ cnt_W1, const float* __restrict__ cnt_W2,
    const float* __restrict__ cbg, const float* __restrict__ cbb,
    const float* __restrict__ cbm, const float* __restrict__ cbv,
    const float* __restrict__ ch_b2, const float* __restrict__ ch_b3,
    const float* __restrict__ cnt_b2,
    short* __restrict__ W1t, short* __restrict__ W2ft, short* __restrict__ W3ft,
    short* __restrict__ cntW1t, short* __restrict__ cntW2ft,
    float* __restrict__ b2f, float* __restrict__ b3f, float* __restrict__ cntb2f) {
    int i = blockIdx.x * 256 + threadIdx.x;
    if (i < 98304) {  // W1t[k][o<128][d<128] <- ch_W1[k][d][o]
        int k = i >> 14, rem = i & 16383, o = rem >> 7, d = rem & 127;
        W1t[i] = f2bf(ch_W1[(k << 14) + (d << 7) + o]);
    } else if ((i -= 98304) < 49152) {  // W2ft[k][o<64][d<128] = A1[k][d]*ch_W2[k][d][o]
        int k = i >> 13, rem = i & 8191, o = rem >> 7, d = rem & 127;
        int ci = (k << 7) + d;
        float A1 = c1g[ci] * rsqrtf(c1v[ci] + EPSL);
        W2ft[i] = f2bf(ch_W2[(k << 13) + (d << 6) + o] * A1);
    } else if ((i -= 49152) < 12288) {  // W3ft[k][o<32][d<64], zero-pad o>=24
        int k = i >> 11, rem = i & 2047, o = rem >> 6, d = rem & 63;
        float val = 0.f;
        if (o < 24) {
            int ci = (k << 6) + d;
            float A2 = c2g[ci] * rsqrtf(c2v[ci] + EPSL);
            val = ch_W3[k * 1536 + d * 24 + o] * A2;
        }
        W3ft[i] = f2bf(val);
    } else if ((i -= 12288) < 8192) {  // cntW1t[o<64][d<128]
        int o = i >> 7, d = i & 127;
        cntW1t[i] = f2bf(cnt_W1[(d << 6) + o]);
    } else if ((i -= 8192) < 1024) {  // cntW2ft[o<16][d<64], zero-pad o>=6
        int o = i >> 6, d = i & 63;
        float val = 0.f;
        if (o < 6) val = cnt_W2[d * 6 + o] * (cbg[d] * rsqrtf(cbv[d] + EPSL));
        cntW2ft[i] = f2bf(val);
    } else if ((i -= 1024) < 384) {  // b2f[k][o<64]
        int k = i >> 6, o = i & 63;
        float s = ch_b2[i];
        for (int d = 0; d < 128; ++d) {
            int ci = (k << 7) + d;
            float A1 = c1g[ci] * rsqrtf(c1v[ci] + EPSL);
            float B1 = c1b[ci] - c1m[ci] * A1;
            s += B1 * ch_W2[(k << 13) + (d << 6) + o];
        }
        b2f[i] = s;
    } else if ((i -= 384) < 144) {  // b3f[k][o<24]
        int k = i / 24, o = i - k * 24;
        float s = ch_b3[i];
        for (int d = 0; d < 64; ++d) {
            int ci = (k << 6) + d;
            float A2 = c2g[ci] * rsqrtf(c2v[ci] + EPSL);
            float B2 = c2b[ci] - c2m[ci] * A2;
            s += B2 * ch_W3[k * 1536 + d * 24 + o];
        }
        b3f[i] = s;
    } else if ((i -= 144) < 6) {  // cntb2f[o<6]
        float s = cnt_b2[i];
        for (int d = 0; d < 64; ++d) {
            float Ac = cbg[d] * rsqrtf(cbv[d] + EPSL);
            float Bc = cbb[d] - cbm[d] * Ac;
            s += Bc * cnt_W2[d * 6 + i];
        }
        cntb2f[i] = s;
    }
}

// ---------- fused agg1 + layer1 (perm-balanced, unroll-4 gather, bf16 out) ----------
__global__ __launch_bounds__(256) void k_agg1_layer1(
    const float* __restrict__ x, const int* __restrict__ rowstart,
    const int* __restrict__ cnt, const int* __restrict__ sorted_src,
    const int* __restrict__ perm,
    const float* __restrict__ W1l, const float* __restrict__ W1r,
    const float* __restrict__ b1,
    const float* __restrict__ g, const float* __restrict__ bb,
    const float* __restrict__ m, const float* __restrict__ v,
    short* __restrict__ h1b) {
    int wave = threadIdx.x >> 6;
    int lane = threadIdx.x & 63;
    int n = perm[blockIdx.x * 4 + wave];
    __shared__ float as[4][F_IN], xs4[4][F_IN];

    int rs = rowstart[n];
    int d = cnt[n];
    if (lane < F_IN) {
        float acc = 0.f;
        int j = 0;
        for (; j + 4 <= d; j += 4) {
            int s0 = sorted_src[rs + j], s1 = sorted_src[rs + j + 1];
            int s2 = sorted_src[rs + j + 2], s3 = sorted_src[rs + j + 3];
            float a0 = x[(size_t)s0 * F_IN + lane];
            float a1 = x[(size_t)s1 * F_IN + lane];
            float a2 = x[(size_t)s2 * F_IN + lane];
            float a3 = x[(size_t)s3 * F_IN + lane];
            acc += (a0 + a1) + (a2 + a3);
        }
        for (; j < d; ++j) acc += x[(size_t)sorted_src[rs + j] * F_IN + lane];
        float inv = 1.0f / fmaxf((float)d, 1.0f);
        as[wave][lane] = acc * inv;
        xs4[wave][lane] = x[(size_t)n * F_IN + lane];
    }
    __syncthreads();

    float a0 = b1[lane], a1 = b1[lane + 64];
    for (int i = 0; i < F_IN; ++i) {
        float av = as[wave][i], xv = xs4[wave][i];
        a0 += av * W1l[i * H + lane] + xv * W1r[i * H + lane];
        a1 += av * W1l[i * H + 64 + lane] + xv * W1r[i * H + 64 + lane];
    }
    int f0 = lane, f1 = lane + 64;
    float y0 = (a0 - m[f0]) * rsqrtf(v[f0] + EPSL) * g[f0] + bb[f0];
    float y1 = (a1 - m[f1]) * rsqrtf(v[f1] + EPSL) * g[f1] + bb[f1];
    h1b[(size_t)n * H + f0] = f2bf(fmaxf(y0, 0.f));
    h1b[(size_t)n * H + f1] = f2bf(fmaxf(y1, 0.f));
}

// ---------- fused agg2 + layer2 v3: bf16 gather (quarter-wave/node) + fp32 reg-tiled GEMM ----------
__global__ __launch_bounds__(256) void k_agg2_layer2(
    const short* __restrict__ h1b, const int* __restrict__ rowstart,
    const int* __restrict__ cnt, const int* __restrict__ sorted_src,
    const int* __restrict__ perm,
    const float* __restrict__ W2l, const float* __restrict__ W2r,
    const float* __restrict__ b2,
    const float* __restrict__ g, const float* __restrict__ bb,
    const float* __restrict__ m, const float* __restrict__ v,
    short* __restrict__ hb) {
    __shared__ float xs[32][256];  // [r][0:128]=agg_mean, [r][128:256]=root h1
    __shared__ int nid[32];
    int t = threadIdx.x;
    int wave = t >> 6, lane = t & 63;
    int q4 = lane >> 4;   // quarter id: which node of the group of 4
    int li = lane & 15;   // 16 lanes x int4 = full 256 B bf16 row
    int n0 = blockIdx.x * 32;

    for (int gq = 0; gq < 2; ++gq) {
        int r = wave * 8 + gq * 4 + q4;
        int n = perm[n0 + r];
        if (li == 0) nid[r] = n;
        int rs = rowstart[n];
        int d = cnt[n];
        float acc[8] = {0.f, 0.f, 0.f, 0.f, 0.f, 0.f, 0.f, 0.f};
        for (int j = 0; j < d; j += 4) {
            int rem = d - j;
            int4 v0 = *(const int4*)&h1b[(size_t)sorted_src[rs + j] * H + li * 8];
            int4 v1 = {0, 0, 0, 0}, v2 = {0, 0, 0, 0}, v3 = {0, 0, 0, 0};
            if (rem > 1) v1 = *(const int4*)&h1b[(size_t)sorted_src[rs + j + 1] * H + li * 8];
            if (rem > 2) v2 = *(const int4*)&h1b[(size_t)sorted_src[rs + j + 2] * H + li * 8];
            if (rem > 3) v3 = *(const int4*)&h1b[(size_t)sorted_src[rs + j + 3] * H + li * 8];
            acc8(acc, v0); acc8(acc, v1); acc8(acc, v2); acc8(acc, v3);
        }
        float inv = 1.f / fmaxf((float)d, 1.f);
        float4 w0 = {acc[0] * inv, acc[1] * inv, acc[2] * inv, acc[3] * inv};
        float4 w1 = {acc[4] * inv, acc[5] * inv, acc[6] * inv, acc[7] * inv};
        *(float4*)&xs[r][8 * li] = w0;
        *(float4*)&xs[r][8 * li + 4] = w1;
        // root row
        float rt[8] = {0.f, 0.f, 0.f, 0.f, 0.f, 0.f, 0.f, 0.f};
        int4 rv = *(const int4*)&h1b[(size_t)n * H + li * 8];
        acc8(rt, rv);
        *(float4*)&xs[r][128 + 8 * li] = *(float4*)&rt[0];
        *(float4*)&xs[r][128 + 8 * li + 4] = *(float4*)&rt[4];
    }
    __syncthreads();

    // GEMM: 32x128 tile, K=128, 4 rows x 4 cols per thread (fp32)
    int cg = t & 31;
    int rg = t >> 5;
    float4 acc2[4] = {};
    for (int k = 0; k < H; ++k) {
        float4 wl = *(const float4*)&W2l[k * H + 4 * cg];
        float4 wr = *(const float4*)&W2r[k * H + 4 * cg];
#pragma unroll
        for (int i = 0; i < 4; ++i) {
            float a = xs[4 * rg + i][k];
            float b = xs[4 * rg + i][128 + k];
            acc2[i].x += a * wl.x + b * wr.x;
            acc2[i].y += a * wl.y + b * wr.y;
            acc2[i].z += a * wl.z + b * wr.z;
            acc2[i].w += a * wl.w + b * wr.w;
        }
    }
    int c0 = 4 * cg;
    float4 bi = *(const float4*)&b2[c0];
    float4 vv = *(const float4*)&v[c0];
    float4 gg = *(const float4*)&g[c0];
    float4 mm = *(const float4*)&m[c0];
    float4 be = *(const float4*)&bb[c0];
    float scx = rsqrtf(vv.x + EPSL) * gg.x;
    float scy = rsqrtf(vv.y + EPSL) * gg.y;
    float scz = rsqrtf(vv.z + EPSL) * gg.z;
    float scw = rsqrtf(vv.w + EPSL) * gg.w;
#pragma unroll
    for (int i = 0; i < 4; ++i) {
        int n = nid[4 * rg + i];
        s16x4 o;
        o.x = f2bf(fmaxf((acc2[i].x + bi.x - mm.x) * scx + be.x, 0.f));
        o.y = f2bf(fmaxf((acc2[i].y + bi.y - mm.y) * scy + be.y, 0.f));
        o.z = f2bf(fmaxf((acc2[i].z + bi.z - mm.z) * scz + be.z, 0.f));
        o.w = f2bf(fmaxf((acc2[i].w + bi.w - mm.w) * scw + be.w, 0.f));
        *(s16x4*)&hb[(size_t)n * H + c0] = o;
    }
}

// ---------- heads via MFMA: 64 nodes/block, 4 waves ----------
__global__ __launch_bounds__(256) void k_heads_mfma(
    const short* __restrict__ hb,
    const float* __restrict__ cntb1, const float* __restrict__ ch_b1,
    const short* __restrict__ W1t, const short* __restrict__ W2ft,
    const short* __restrict__ W3ft, const short* __restrict__ cntW1t,
    const short* __restrict__ cntW2ft,
    const float* __restrict__ b2f, const float* __restrict__ b3f,
    const float* __restrict__ cntb2f,
    float* __restrict__ out) {
    __shared__ short hs[64 * LDH];
    __shared__ short z1[64 * LDH];
    __shared__ short z2[64 * LDZ];
    __shared__ short wst[64 * LDH];

    int t = threadIdx.x;
    int lane = t & 63, w = t >> 6;
    int lr = lane & 15, lk = lane >> 4;
    int n0 = blockIdx.x * 64;

#pragma unroll
    for (int it = 0; it < 4; ++it) {
        int idx = t * 8 + it * 2048;
        int r = idx >> 7, c = idx & 127;
        int n = n0 + r;
        if (n > N_NODES - 1) n = N_NODES - 1;
        *(int4*)&hs[r * LDH + c] = *(const int4*)&hb[(size_t)n * 128 + c];
    }
    __syncthreads();

    // ===== count head =====
#pragma unroll
    for (int it = 0; it < 4; ++it) {
        int idx = t * 8 + it * 2048;
        int r = idx >> 7, c = idx & 127;
        *(int4*)&wst[r * LDH + c] = *(const int4*)&cntW1t[idx];
    }
    __syncthreads();
    {
        f32x4 acc[4] = {};
#pragma unroll
        for (int ks = 0; ks < 4; ++ks) {
            bf16x8 a = *(bf16x8*)&hs[(16 * w + lr) * LDH + 32 * ks + lk * 8];
#pragma unroll
            for (int ct = 0; ct < 4; ++ct) {
                bf16x8 b = *(bf16x8*)&wst[(16 * ct + lr) * LDH + 32 * ks + lk * 8];
                acc[ct] = __builtin_amdgcn_mfma_f32_16x16x32_bf16(a, b, acc[ct], 0, 0, 0);
            }
        }
        __syncthreads();
#pragma unroll
        for (int ct = 0; ct < 4; ++ct) {
            int c = 16 * ct + lr;
            float bi = cntb1[c];
#pragma unroll
            for (int j = 0; j < 4; ++j) {
                int r = 16 * w + lk * 4 + j;
                z2[r * LDZ + c] = f2bf(fmaxf(acc[ct][j] + bi, 0.f));
            }
        }
    }
    {
        int idx = t * 8;
        if (idx < 16 * 64) {
            int r = idx >> 6, c = idx & 63;
            *(int4*)&wst[r * LDZ + c] = *(const int4*)&cntW2ft[idx];
        }
    }
    __syncthreads();
    {
        f32x4 acc = {};
#pragma unroll
        for (int ks = 0; ks < 2; ++ks) {
            bf16x8 a = *(bf16x8*)&z2[(16 * w + lr) * LDZ + 32 * ks + lk * 8];
            bf16x8 b = *(bf16x8*)&wst[lr * LDZ + 32 * ks + lk * 8];
            acc = __builtin_amdgcn_mfma_f32_16x16x32_bf16(a, b, acc, 0, 0, 0);
        }
        if (lr < 6) {
            float bi = cntb2f[lr];
#pragma unroll
            for (int j = 0; j < 4; ++j) {
                int r = 16 * w + lk * 4 + j, n = n0 + r;
                if (n < N_NODES) out[(size_t)n * OUT_F + lr] = acc[j] + bi;
            }
        }
    }
    __syncthreads();

    // ===== coord heads =====
    for (int k = 0; k < K_TYPES; ++k) {
        const short* W1k = W1t + k * 16384;
        for (int half = 0; half < 2; ++half) {
#pragma unroll
            for (int it = 0; it < 4; ++it) {
                int idx = t * 8 + it * 2048;
                int r = idx >> 7, c = idx & 127;
                *(int4*)&wst[r * LDH + c] = *(const int4*)&W1k[half * 8192 + idx];
            }
            __syncthreads();
            f32x4 acc[4] = {};
#pragma unroll
            for (int ks = 0; ks < 4; ++ks) {
                bf16x8 a = *(bf16x8*)&hs[(16 * w + lr) * LDH + 32 * ks + lk * 8];
#pragma unroll
                for (int ct = 0; ct < 4; ++ct) {
                    bf16x8 b = *(bf16x8*)&wst[(16 * ct + lr) * LDH + 32 * ks + lk * 8];
                    acc[ct] = __builtin_amdgcn_mfma_f32_16x16x32_bf16(a, b, acc[ct], 0, 0, 0);
                }
            }
            __syncthreads();
#pragma unroll
            for (int ct = 0; ct < 4; ++ct) {
                int c = 64 * half + 16 * ct + lr;
                float bi = ch_b1[k * 128 + c];
#pragma unroll
                for (int j = 0; j < 4; ++j) {
                    int r = 16 * w + lk * 4 + j;
                    z1[r * LDH + c] = f2bf(fmaxf(acc[ct][j] + bi, 0.f));
                }
            }
        }
#pragma unroll
        for (int it = 0; it < 4; ++it) {
            int idx = t * 8 + it * 2048;
            int r = idx >> 7, c = idx & 127;
            *(int4*)&wst[r * LDH + c] = *(const int4*)&W2ft[k * 8192 + idx];
        }
        __syncthreads();
        {
            f32x4 acc[4] = {};
#pragma unroll
            for (int ks = 0; ks < 4; ++ks) {
                bf16x8 a = *(bf16x8*)&z1[(16 * w + lr) * LDH + 32 * ks + lk * 8];
#pragma unroll
                for (int ct = 0; ct < 4; ++ct) {
                    bf16x8 b = *(bf16x8*)&wst[(16 * ct + lr) * LDH + 32 * ks + lk * 8];
                    acc[ct] = __builtin_amdgcn_mfma_f32_16x16x32_bf16(a, b, acc[ct], 0, 0, 0);
                }
            }
            __syncthreads();
#pragma unroll
            for (int ct = 0; ct < 4; ++ct) {
                int c = 16 * ct + lr;
                float bi = b2f[k * 64 + c];
#pragma unroll
                for (int j = 0; j < 4; ++j) {
                    int r = 16 * w + lk * 4 + j;
                    z2[r * LDZ + c] = f2bf(fmaxf(acc[ct][j] + bi, 0.f));
                }
            }
        }
        {
            int idx = t * 8;
            int r = idx >> 6, c = idx & 63;
            *(int4*)&wst[r * LDZ + c] = *(const int4*)&W3ft[k * 2048 + idx];
        }
        __syncthreads();
        {
            f32x4 acc[2] = {};
#pragma unroll
            for (int ks = 0; ks < 2; ++ks) {
                bf16x8 a = *(bf16x8*)&z2[(16 * w + lr) * LDZ + 32 * ks + lk * 8];
#pragma unroll
                for (int ct = 0; ct < 2; ++ct) {
                    bf16x8 b = *(bf16x8*)&wst[(16 * ct + lr) * LDZ + 32 * ks + lk * 8];
                    acc[ct] = __builtin_amdgcn_mfma_f32_16x16x32_bf16(a, b, acc[ct], 0, 0, 0);
                }
            }
#pragma unroll
            for (int ct = 0; ct < 2; ++ct) {
                int c = 16 * ct + lr;
                if (c < 24) {
                    float bi = b3f[k * 24 + c];
#pragma unroll
                    for (int j = 0; j < 4; ++j) {
                        int r = 16 * w + lk * 4 + j, n = n0 + r;
                        if (n < N_NODES)
                            out[(size_t)n * OUT_F + 6 + 24 * k + c] =
                                1.f / (1.f + expf(-(acc[ct][j] + bi)));
                    }
                }
            }
        }
        __syncthreads();
    }
}

extern "C" void kernel_launch(void* const* d_in, const int* in_sizes, int n_in,
                              void* d_out, int out_size, void* d_ws, size_t ws_size,
                              hipStream_t stream) {
    const float* x = (const float*)d_in[0];
    const int* ei = (const int*)d_in[1];
    const float* W1l = (const float*)d_in[2];
    const float* W1r = (const float*)d_in[3];
    const float* b1 = (const float*)d_in[4];
    const float* bn1_g = (const float*)d_in[5];
    const float* bn1_b = (const float*)d_in[6];
    const float* bn1_m = (const float*)d_in[7];
    const float* bn1_v = (const float*)d_in[8];
    const float* W2l = (const float*)d_in[9];
    const float* W2r = (const float*)d_in[10];
    const float* b2 = (const float*)d_in[11];
    const float* bn2_g = (const float*)d_in[12];
    const float* bn2_b = (const float*)d_in[13];
    const float* bn2_m = (const float*)d_in[14];
    const float* bn2_v = (const float*)d_in[15];
    const float* cnt_W1 = (const float*)d_in[16];
    const float* cnt_b1 = (const float*)d_in[17];
    const float* cnt_bn_g = (const float*)d_in[18];
    const float* cnt_bn_b = (const float*)d_in[19];
    const float* cnt_bn_m = (const float*)d_in[20];
    const float* cnt_bn_v = (const float*)d_in[21];
    const float* cnt_W2 = (const float*)d_in[22];
    const float* cnt_b2 = (const float*)d_in[23];
    const float* ch_W1 = (const float*)d_in[24];
    const float* ch_b1 = (const float*)d_in[25];
    const float* ch_bn1_g = (const float*)d_in[26];
    const float* ch_bn1_b = (const float*)d_in[27];
    const float* ch_bn1_m = (const float*)d_in[28];
    const float* ch_bn1_v = (const float*)d_in[29];
    const float* ch_W2 = (const float*)d_in[30];
    const float* ch_b2 = (const float*)d_in[31];
    const float* ch_bn2_g = (const float*)d_in[32];
    const float* ch_bn2_b = (const float*)d_in[33];
    const float* ch_bn2_m = (const float*)d_in[34];
    const float* ch_bn2_v = (const float*)d_in[35];
    const float* ch_W3 = (const float*)d_in[36];
    const float* ch_b3 = (const float*)d_in[37];

    float* out = (float*)d_out;

    // workspace (ints): cnt[N] | dbins[64] | dcur[64] | rowstart[N] | cursor[N]
    //                   | blocksums[512] | perm[N] | sorted_src[E]
    // then (shorts): h1b[N*H] | hb[N*H] | W1t | W2ft | W3ft | cntW1t | cntW2ft
    // then (floats): b2f | b3f | cntb2f
    int* cnt = (int*)d_ws;
    int* dbins = cnt + N_NODES;
    int* dcur = dbins + 64;
    int* rowstart = dcur + 64;
    int* cursor = rowstart + N_NODES;
    int* blocksums = cursor + N_NODES;
    int* perm = blocksums + 512;
    int* sorted_src = perm + N_NODES;
    short* h1b = (short*)(sorted_src + N_EDGES);
    short* hb = h1b + (size_t)N_NODES * H;
    short* W1t = hb + (size_t)N_NODES * H;
    short* W2ft = W1t + 98304;
    short* W3ft = W2ft + 49152;
    short* cntW1t = W3ft + 12288;
    short* cntW2ft = cntW1t + 8192;
    float* b2f = (float*)(cntW2ft + 1024);
    float* b3f = b2f + 384;
    float* cntb2f = b3f + 144;

    // zero histogram + degree bins (contiguous)
    hipMemsetAsync(cnt, 0, (N_NODES + 64) * sizeof(int), stream);

    k_prep<<<663, 256, 0, stream>>>(ch_W1, ch_W2, ch_W3,
                                    ch_bn1_g, ch_bn1_b, ch_bn1_m, ch_bn1_v,
                                    ch_bn2_g, ch_bn2_b, ch_bn2_m, ch_bn2_v,
                                    cnt_W1, cnt_W2,
                                    cnt_bn_g, cnt_bn_b, cnt_bn_m, cnt_bn_v,
                                    ch_b2, ch_b3, cnt_b2,
                                    W1t, W2ft, W3ft, cntW1t, cntW2ft,
                                    b2f, b3f, cntb2f);

    k_hist<<<N_EDGES / 256, 256, 0, stream>>>(ei, cnt);
    k_scan1<<<SCAN_BLOCKS, 256, 0, stream>>>(cnt, rowstart, blocksums);
    k_scan2<<<1, 512, 0, stream>>>(blocksums);
    k_scan3<<<SCAN_BLOCKS, 256, 0, stream>>>(rowstart, blocksums, cursor);
    k_fill<<<N_EDGES / 256, 256, 0, stream>>>(ei, cursor, sorted_src);

    k_deghist<<<SCAN_BLOCKS, 256, 0, stream>>>(cnt, dbins);
    k_degscan<<<1, 64, 0, stream>>>(dbins, dcur);
    k_degscatter<<<SCAN_BLOCKS, 256, 0, stream>>>(cnt, dcur, perm);

    k_agg1_layer1<<<N_NODES / 4, 256, 0, stream>>>(x, rowstart, cnt, sorted_src, perm,
                                                   W1l, W1r, b1,
                                                   bn1_g, bn1_b, bn1_m, bn1_v, h1b);
    k_agg2_layer2<<<N_NODES / 32, 256, 0, stream>>>(h1b, rowstart, cnt, sorted_src, perm,
                                                    W2l, W2r, b2,
                                                    bn2_g, bn2_b, bn2_m, bn2_v, hb);
    k_heads_mfma<<<(N_NODES + 63) / 64, 256, 0, stream>>>(
        hb, cnt_b1, ch_b1, W1t, W2ft, W3ft, cntW1t, cntW2ft,
        b2f, b3f, cntb2f, out);
}

// Round 6
// 817.049 us; speedup vs baseline: 1.0827x; 1.0827x over previous
//
#include <hip/hip_runtime.h>

#define N_NODES 100000
#define N_EDGES 1600000
#define F_IN 17
#define H 128
#define K_TYPES 6
#define MD 12
#define OUT_F 150
#define EPSL 1e-5f

#define SCAN_BLOCKS 391  // ceil(100000/256)

#define LDH 136  // LDS row stride (bf16) for 128-col tiles
#define LDZ 72   // LDS row stride (bf16) for 64-col tiles

typedef __attribute__((ext_vector_type(8))) short bf16x8;
typedef __attribute__((ext_vector_type(4))) float f32x4;
typedef __attribute__((ext_vector_type(4))) short s16x4;

static __device__ __forceinline__ short f2bf(float f) {
    union { float f; unsigned u; } v;
    v.f = f;
    unsigned r = (v.u + 0x7FFF + ((v.u >> 16) & 1)) >> 16;  // RNE
    return (short)r;
}

// unpack int4 = 8 bf16 and accumulate into acc[0..7]
static __device__ __forceinline__ void acc8(float* a, int4 u) {
    union { unsigned u; float f; } lo, hi;
    lo.u = ((unsigned)u.x) << 16; hi.u = ((unsigned)u.x) & 0xFFFF0000u; a[0] += lo.f; a[1] += hi.f;
    lo.u = ((unsigned)u.y) << 16; hi.u = ((unsigned)u.y) & 0xFFFF0000u; a[2] += lo.f; a[3] += hi.f;
    lo.u = ((unsigned)u.z) << 16; hi.u = ((unsigned)u.z) & 0xFFFF0000u; a[4] += lo.f; a[5] += hi.f;
    lo.u = ((unsigned)u.w) << 16; hi.u = ((unsigned)u.w) & 0xFFFF0000u; a[6] += lo.f; a[7] += hi.f;
}

// ---------- CSR build: histogram ----------
__global__ __launch_bounds__(256) void k_hist(const int* __restrict__ ei,
                                              int* __restrict__ cnt) {
    int e = blockIdx.x * 256 + threadIdx.x;
    int dst = ei[N_EDGES + e];
    atomicAdd(&cnt[dst], 1);
}

// ---------- CSR build: scan stage 1 ----------
__global__ __launch_bounds__(256) void k_scan1(const int* __restrict__ cnt,
                                               int* __restrict__ rowstart,
                                               int* __restrict__ blocksums) {
    __shared__ int s[256];
    int tid = threadIdx.x;
    int i = blockIdx.x * 256 + tid;
    int v = (i < N_NODES) ? cnt[i] : 0;
    s[tid] = v;
    __syncthreads();
    for (int off = 1; off < 256; off <<= 1) {
        int t = (tid >= off) ? s[tid - off] : 0;
        __syncthreads();
        s[tid] += t;
        __syncthreads();
    }
    if (i < N_NODES) rowstart[i] = s[tid] - v;
    if (tid == 255) blocksums[blockIdx.x] = s[255];
}

// ---------- CSR build: scan stage 2 ----------
__global__ __launch_bounds__(512) void k_scan2(int* __restrict__ blocksums) {
    __shared__ int s[512];
    int t = threadIdx.x;
    int v0 = (t < SCAN_BLOCKS) ? blocksums[t] : 0;
    s[t] = v0;
    __syncthreads();
    for (int off = 1; off < 512; off <<= 1) {
        int tv = (t >= off) ? s[t - off] : 0;
        __syncthreads();
        s[t] += tv;
        __syncthreads();
    }
    if (t < SCAN_BLOCKS) blocksums[t] = s[t] - v0;
}

// ---------- CSR build: scan stage 3 ----------
__global__ __launch_bounds__(256) void k_scan3(int* __restrict__ rowstart,
                                               const int* __restrict__ blocksums,
                                               int* __restrict__ cursor) {
    int i = blockIdx.x * 256 + threadIdx.x;
    if (i < N_NODES) {
        int r = rowstart[i] + blocksums[blockIdx.x];
        rowstart[i] = r;
        cursor[i] = r;
    }
}

// ---------- CSR build: fill ----------
__global__ __launch_bounds__(256) void k_fill(const int* __restrict__ ei,
                                              int* __restrict__ cursor,
                                              int* __restrict__ sorted_src) {
    int e = blockIdx.x * 256 + threadIdx.x;
    int src = ei[e];
    int dst = ei[N_EDGES + e];
    int pos = atomicAdd(&cursor[dst], 1);
    sorted_src[pos] = src;
}

// ---------- degree sort: global histogram over clamped degree ----------
__global__ __launch_bounds__(256) void k_deghist(const int* __restrict__ cnt,
                                                 int* __restrict__ dbins) {
    __shared__ int lb[64];
    int t = threadIdx.x;
    if (t < 64) lb[t] = 0;
    __syncthreads();
    int i = blockIdx.x * 256 + t;
    if (i < N_NODES) {
        int d = cnt[i]; if (d > 63) d = 63;
        atomicAdd(&lb[d], 1);
    }
    __syncthreads();
    if (t < 64 && lb[t] > 0) atomicAdd(&dbins[t], lb[t]);
}

// ---------- degree sort: exclusive scan of 64 bins ----------
__global__ __launch_bounds__(64) void k_degscan(const int* __restrict__ dbins,
                                                int* __restrict__ dcur) {
    __shared__ int s[64];
    int t = threadIdx.x;
    int v = dbins[t];
    s[t] = v;
    __syncthreads();
    for (int off = 1; off < 64; off <<= 1) {
        int tv = (t >= off) ? s[t - off] : 0;
        __syncthreads();
        s[t] += tv;
        __syncthreads();
    }
    dcur[t] = s[t] - v;
}

// ---------- degree sort: block-chunked scatter (contention-free) ----------
__global__ __launch_bounds__(256) void k_degscatter(const int* __restrict__ cnt,
                                                    int* __restrict__ dcur,
                                                    int* __restrict__ perm) {
    __shared__ int lb[64];
    __shared__ int lbase[64];
    int t = threadIdx.x;
    if (t < 64) lb[t] = 0;
    __syncthreads();
    int i = blockIdx.x * 256 + t;
    int d = 0, lrank = 0;
    bool act = (i < N_NODES);
    if (act) {
        d = cnt[i]; if (d > 63) d = 63;
        lrank = atomicAdd(&lb[d], 1);  // LDS atomic: cheap
    }
    __syncthreads();
    if (t < 64 && lb[t] > 0) lbase[t] = atomicAdd(&dcur[t], lb[t]);  // 1 per (block,bin)
    __syncthreads();
    if (act) perm[lbase[d] + lrank] = i;
}

// ---------- prep: BN-fold + transpose + bf16-convert head weights ----------
__global__ __launch_bounds__(256) void k_prep(
    const float* __restrict__ ch_W1, const float* __restrict__ ch_W2,
    const float* __restrict__ ch_W3,
    const float* __restrict__ c1g, const float* __restrict__ c1b,
    const float* __restrict__ c1m, const float* __restrict__ c1v,
    const float* __restrict__ c2g, const float* __restrict__ c2b,
    const float* __restrict__ c2m, const float* __restrict__ c2v,
    const float* __restrict__ cnt_W1, const float* __restrict__ cnt_W2,
    const float* __restrict__ cbg, const float* __restrict__ cbb,
    const float* __restrict__ cbm, const float* __restrict__ cbv,
    const float* __restrict__ ch_b2, const float* __restrict__ ch_b3,
    const float* __restrict__ cnt_b2,
    short* __restrict__ W1t, short* __restrict__ W2ft, short* __restrict__ W3ft,
    short* __restrict__ cntW1t, short* __restrict__ cntW2ft,
    float* __restrict__ b2f, float* __restrict__ b3f, float* __restrict__ cntb2f) {
    int i = blockIdx.x * 256 + threadIdx.x;
    if (i < 98304) {  // W1t[k][o<128][d<128] <- ch_W1[k][d][o]
        int k = i >> 14, rem = i & 16383, o = rem >> 7, d = rem & 127;
        W1t[i] = f2bf(ch_W1[(k << 14) + (d << 7) + o]);
    } else if ((i -= 98304) < 49152) {  // W2ft[k][o<64][d<128] = A1[k][d]*ch_W2[k][d][o]
        int k = i >> 13, rem = i & 8191, o = rem >> 7, d = rem & 127;
        int ci = (k << 7) + d;
        float A1 = c1g[ci] * rsqrtf(c1v[ci] + EPSL);
        W2ft[i] = f2bf(ch_W2[(k << 13) + (d << 6) + o] * A1);
    } else if ((i -= 49152) < 12288) {  // W3ft[k][o<32][d<64], zero-pad o>=24
        int k = i >> 11, rem = i & 2047, o = rem >> 6, d = rem & 63;
        float val = 0.f;
        if (o < 24) {
            int ci = (k << 6) + d;
            float A2 = c2g[ci] * rsqrtf(c2v[ci] + EPSL);
            val = ch_W3[k * 1536 + d * 24 + o] * A2;
        }
        W3ft[i] = f2bf(val);
    } else if ((i -= 12288) < 8192) {  // cntW1t[o<64][d<128]
        int o = i >> 7, d = i & 127;
        cntW1t[i] = f2bf(cnt_W1[(d << 6) + o]);
    } else if ((i -= 8192) < 1024) {  // cntW2ft[o<16][d<64], zero-pad o>=6
        int o = i >> 6, d = i & 63;
        float val = 0.f;
        if (o < 6) val = cnt_W2[d * 6 + o] * (cbg[d] * rsqrtf(cbv[d] + EPSL));
        cntW2ft[i] = f2bf(val);
    } else if ((i -= 1024) < 384) {  // b2f[k][o<64]
        int k = i >> 6, o = i & 63;
        float s = ch_b2[i];
        for (int d = 0; d < 128; ++d) {
            int ci = (k << 7) + d;
            float A1 = c1g[ci] * rsqrtf(c1v[ci] + EPSL);
            float B1 = c1b[ci] - c1m[ci] * A1;
            s += B1 * ch_W2[(k << 13) + (d << 6) + o];
        }
        b2f[i] = s;
    } else if ((i -= 384) < 144) {  // b3f[k][o<24]
        int k = i / 24, o = i - k * 24;
        float s = ch_b3[i];
        for (int d = 0; d < 64; ++d) {
            int ci = (k << 6) + d;
            float A2 = c2g[ci] * rsqrtf(c2v[ci] + EPSL);
            float B2 = c2b[ci] - c2m[ci] * A2;
            s += B2 * ch_W3[k * 1536 + d * 24 + o];
        }
        b3f[i] = s;
    } else if ((i -= 144) < 6) {  // cntb2f[o<6]
        float s = cnt_b2[i];
        for (int d = 0; d < 64; ++d) {
            float Ac = cbg[d] * rsqrtf(cbv[d] + EPSL);
            float Bc = cbb[d] - cbm[d] * Ac;
            s += Bc * cnt_W2[d * 6 + i];
        }
        cntb2f[i] = s;
    }
}

// ---------- fused agg1 + layer1 (perm-balanced, unroll-4 gather, bf16 out) ----------
__global__ __launch_bounds__(256) void k_agg1_layer1(
    const float* __restrict__ x, const int* __restrict__ rowstart,
    const int* __restrict__ cnt, const int* __restrict__ sorted_src,
    const int* __restrict__ perm,
    const float* __restrict__ W1l, const float* __restrict__ W1r,
    const float* __restrict__ b1,
    const float* __restrict__ g, const float* __restrict__ bb,
    const float* __restrict__ m, const float* __restrict__ v,
    short* __restrict__ h1b) {
    int wave = threadIdx.x >> 6;
    int lane = threadIdx.x & 63;
    int n = perm[blockIdx.x * 4 + wave];
    __shared__ float as[4][F_IN], xs4[4][F_IN];

    int rs = rowstart[n];
    int d = cnt[n];
    if (lane < F_IN) {
        float acc = 0.f;
        int j = 0;
        for (; j + 4 <= d; j += 4) {
            int s0 = sorted_src[rs + j], s1 = sorted_src[rs + j + 1];
            int s2 = sorted_src[rs + j + 2], s3 = sorted_src[rs + j + 3];
            float a0 = x[(size_t)s0 * F_IN + lane];
            float a1 = x[(size_t)s1 * F_IN + lane];
            float a2 = x[(size_t)s2 * F_IN + lane];
            float a3 = x[(size_t)s3 * F_IN + lane];
            acc += (a0 + a1) + (a2 + a3);
        }
        for (; j < d; ++j) acc += x[(size_t)sorted_src[rs + j] * F_IN + lane];
        float inv = 1.0f / fmaxf((float)d, 1.0f);
        as[wave][lane] = acc * inv;
        xs4[wave][lane] = x[(size_t)n * F_IN + lane];
    }
    __syncthreads();

    float a0 = b1[lane], a1 = b1[lane + 64];
    for (int i = 0; i < F_IN; ++i) {
        float av = as[wave][i], xv = xs4[wave][i];
        a0 += av * W1l[i * H + lane] + xv * W1r[i * H + lane];
        a1 += av * W1l[i * H + 64 + lane] + xv * W1r[i * H + 64 + lane];
    }
    int f0 = lane, f1 = lane + 64;
    float y0 = (a0 - m[f0]) * rsqrtf(v[f0] + EPSL) * g[f0] + bb[f0];
    float y1 = (a1 - m[f1]) * rsqrtf(v[f1] + EPSL) * g[f1] + bb[f1];
    h1b[(size_t)n * H + f0] = f2bf(fmaxf(y0, 0.f));
    h1b[(size_t)n * H + f1] = f2bf(fmaxf(y1, 0.f));
}

// ---------- fused agg2 + layer2 v3: bf16 gather (quarter-wave/node) + fp32 reg-tiled GEMM ----------
__global__ __launch_bounds__(256) void k_agg2_layer2(
    const short* __restrict__ h1b, const int* __restrict__ rowstart,
    const int* __restrict__ cnt, const int* __restrict__ sorted_src,
    const int* __restrict__ perm,
    const float* __restrict__ W2l, const float* __restrict__ W2r,
    const float* __restrict__ b2,
    const float* __restrict__ g, const float* __restrict__ bb,
    const float* __restrict__ m, const float* __restrict__ v,
    short* __restrict__ hb) {
    __shared__ float xs[32][256];  // [r][0:128]=agg_mean, [r][128:256]=root h1
    __shared__ int nid[32];
    int t = threadIdx.x;
    int wave = t >> 6, lane = t & 63;
    int q4 = lane >> 4;
    int li = lane & 15;
    int n0 = blockIdx.x * 32;

    for (int gq = 0; gq < 2; ++gq) {
        int r = wave * 8 + gq * 4 + q4;
        int n = perm[n0 + r];
        if (li == 0) nid[r] = n;
        int rs = rowstart[n];
        int d = cnt[n];
        float acc[8] = {0.f, 0.f, 0.f, 0.f, 0.f, 0.f, 0.f, 0.f};
        for (int j = 0; j < d; j += 4) {
            int rem = d - j;
            int4 v0 = *(const int4*)&h1b[(size_t)sorted_src[rs + j] * H + li * 8];
            int4 v1 = {0, 0, 0, 0}, v2 = {0, 0, 0, 0}, v3 = {0, 0, 0, 0};
            if (rem > 1) v1 = *(const int4*)&h1b[(size_t)sorted_src[rs + j + 1] * H + li * 8];
            if (rem > 2) v2 = *(const int4*)&h1b[(size_t)sorted_src[rs + j + 2] * H + li * 8];
            if (rem > 3) v3 = *(const int4*)&h1b[(size_t)sorted_src[rs + j + 3] * H + li * 8];
            acc8(acc, v0); acc8(acc, v1); acc8(acc, v2); acc8(acc, v3);
        }
        float inv = 1.f / fmaxf((float)d, 1.f);
        float4 w0 = {acc[0] * inv, acc[1] * inv, acc[2] * inv, acc[3] * inv};
        float4 w1 = {acc[4] * inv, acc[5] * inv, acc[6] * inv, acc[7] * inv};
        *(float4*)&xs[r][8 * li] = w0;
        *(float4*)&xs[r][8 * li + 4] = w1;
        float rt[8] = {0.f, 0.f, 0.f, 0.f, 0.f, 0.f, 0.f, 0.f};
        int4 rv = *(const int4*)&h1b[(size_t)n * H + li * 8];
        acc8(rt, rv);
        *(float4*)&xs[r][128 + 8 * li] = *(float4*)&rt[0];
        *(float4*)&xs[r][128 + 8 * li + 4] = *(float4*)&rt[4];
    }
    __syncthreads();

    int cg = t & 31;
    int rg = t >> 5;
    float4 acc2[4] = {};
    for (int k = 0; k < H; ++k) {
        float4 wl = *(const float4*)&W2l[k * H + 4 * cg];
        float4 wr = *(const float4*)&W2r[k * H + 4 * cg];
#pragma unroll
        for (int i = 0; i < 4; ++i) {
            float a = xs[4 * rg + i][k];
            float b = xs[4 * rg + i][128 + k];
            acc2[i].x += a * wl.x + b * wr.x;
            acc2[i].y += a * wl.y + b * wr.y;
            acc2[i].z += a * wl.z + b * wr.z;
            acc2[i].w += a * wl.w + b * wr.w;
        }
    }
    int c0 = 4 * cg;
    float4 bi = *(const float4*)&b2[c0];
    float4 vv = *(const float4*)&v[c0];
    float4 gg = *(const float4*)&g[c0];
    float4 mm = *(const float4*)&m[c0];
    float4 be = *(const float4*)&bb[c0];
    float scx = rsqrtf(vv.x + EPSL) * gg.x;
    float scy = rsqrtf(vv.y + EPSL) * gg.y;
    float scz = rsqrtf(vv.z + EPSL) * gg.z;
    float scw = rsqrtf(vv.w + EPSL) * gg.w;
#pragma unroll
    for (int i = 0; i < 4; ++i) {
        int n = nid[4 * rg + i];
        s16x4 o;
        o.x = f2bf(fmaxf((acc2[i].x + bi.x - mm.x) * scx + be.x, 0.f));
        o.y = f2bf(fmaxf((acc2[i].y + bi.y - mm.y) * scy + be.y, 0.f));
        o.z = f2bf(fmaxf((acc2[i].z + bi.z - mm.z) * scz + be.z, 0.f));
        o.w = f2bf(fmaxf((acc2[i].w + bi.w - mm.w) * scw + be.w, 0.f));
        *(s16x4*)&hb[(size_t)n * H + c0] = o;
    }
}

// ---------- heads via MFMA v2: B-fragments direct from global (L1/L2-resident), no wst ----------
__global__ __launch_bounds__(256) void k_heads_mfma(
    const short* __restrict__ hb,
    const float* __restrict__ cntb1, const float* __restrict__ ch_b1,
    const short* __restrict__ W1t, const short* __restrict__ W2ft,
    const short* __restrict__ W3ft, const short* __restrict__ cntW1t,
    const short* __restrict__ cntW2ft,
    const float* __restrict__ b2f, const float* __restrict__ b3f,
    const float* __restrict__ cntb2f,
    float* __restrict__ out) {
    __shared__ short hs[64 * LDH];
    __shared__ short z1[64 * LDH];
    __shared__ short z2[64 * LDZ];

    int t = threadIdx.x;
    int lane = t & 63, w = t >> 6;
    int lr = lane & 15, lk = lane >> 4;
    int n0 = blockIdx.x * 64;

#pragma unroll
    for (int it = 0; it < 4; ++it) {
        int idx = t * 8 + it * 2048;
        int r = idx >> 7, c = idx & 127;
        int n = n0 + r;
        if (n > N_NODES - 1) n = N_NODES - 1;
        *(int4*)&hs[r * LDH + c] = *(const int4*)&hb[(size_t)n * 128 + c];
    }
    __syncthreads();

    // ===== count head G1: hs(64x128) @ cntW1t^T -> z2 (64x64) =====
    {
        f32x4 acc[4] = {};
#pragma unroll
        for (int ks = 0; ks < 4; ++ks) {
            bf16x8 a = *(bf16x8*)&hs[(16 * w + lr) * LDH + 32 * ks + lk * 8];
#pragma unroll
            for (int ct = 0; ct < 4; ++ct) {
                bf16x8 b = *(const bf16x8*)&cntW1t[(16 * ct + lr) * 128 + 32 * ks + lk * 8];
                acc[ct] = __builtin_amdgcn_mfma_f32_16x16x32_bf16(a, b, acc[ct], 0, 0, 0);
            }
        }
#pragma unroll
        for (int ct = 0; ct < 4; ++ct) {
            int c = 16 * ct + lr;
            float bi = cntb1[c];
#pragma unroll
            for (int j = 0; j < 4; ++j) {
                int r = 16 * w + lk * 4 + j;
                z2[r * LDZ + c] = f2bf(fmaxf(acc[ct][j] + bi, 0.f));
            }
        }
    }
    __syncthreads();
    // ===== count head G2: z2 @ cntW2ft^T -> out[:, 0:6] =====
    {
        f32x4 acc = {};
#pragma unroll
        for (int ks = 0; ks < 2; ++ks) {
            bf16x8 a = *(bf16x8*)&z2[(16 * w + lr) * LDZ + 32 * ks + lk * 8];
            bf16x8 b = *(const bf16x8*)&cntW2ft[lr * 64 + 32 * ks + lk * 8];
            acc = __builtin_amdgcn_mfma_f32_16x16x32_bf16(a, b, acc, 0, 0, 0);
        }
        if (lr < 6) {
            float bi = cntb2f[lr];
#pragma unroll
            for (int j = 0; j < 4; ++j) {
                int r = 16 * w + lk * 4 + j, n = n0 + r;
                if (n < N_NODES) out[(size_t)n * OUT_F + lr] = acc[j] + bi;
            }
        }
    }

    // ===== coord heads =====
    for (int k = 0; k < K_TYPES; ++k) {
        const short* W1k = W1t + k * 16384;
        // G1: hs(64x128) @ W1k^T -> z1(64x128); B direct from global, no inner syncs
#pragma unroll
        for (int half = 0; half < 2; ++half) {
            f32x4 acc[4] = {};
#pragma unroll
            for (int ks = 0; ks < 4; ++ks) {
                bf16x8 a = *(bf16x8*)&hs[(16 * w + lr) * LDH + 32 * ks + lk * 8];
#pragma unroll
                for (int ct = 0; ct < 4; ++ct) {
                    int o = 64 * half + 16 * ct + lr;
                    bf16x8 b = *(const bf16x8*)&W1k[o * 128 + 32 * ks + lk * 8];
                    acc[ct] = __builtin_amdgcn_mfma_f32_16x16x32_bf16(a, b, acc[ct], 0, 0, 0);
                }
            }
#pragma unroll
            for (int ct = 0; ct < 4; ++ct) {
                int c = 64 * half + 16 * ct + lr;
                float bi = ch_b1[k * 128 + c];
#pragma unroll
                for (int j = 0; j < 4; ++j) {
                    int r = 16 * w + lk * 4 + j;
                    z1[r * LDH + c] = f2bf(fmaxf(acc[ct][j] + bi, 0.f));
                }
            }
        }
        __syncthreads();  // z1 ready; also: all prior z2 readers done
        // G2: z1(64x128) @ W2ft^T -> z2(64x64)
        {
            f32x4 acc[4] = {};
#pragma unroll
            for (int ks = 0; ks < 4; ++ks) {
                bf16x8 a = *(bf16x8*)&z1[(16 * w + lr) * LDH + 32 * ks + lk * 8];
#pragma unroll
                for (int ct = 0; ct < 4; ++ct) {
                    bf16x8 b = *(const bf16x8*)&W2ft[k * 8192 + (16 * ct + lr) * 128 + 32 * ks + lk * 8];
                    acc[ct] = __builtin_amdgcn_mfma_f32_16x16x32_bf16(a, b, acc[ct], 0, 0, 0);
                }
            }
#pragma unroll
            for (int ct = 0; ct < 4; ++ct) {
                int c = 16 * ct + lr;
                float bi = b2f[k * 64 + c];
#pragma unroll
                for (int j = 0; j < 4; ++j) {
                    int r = 16 * w + lk * 4 + j;
                    z2[r * LDZ + c] = f2bf(fmaxf(acc[ct][j] + bi, 0.f));
                }
            }
        }
        __syncthreads();  // z2 ready
        // G3: z2(64x64) @ W3ft^T -> sigmoid -> out
        {
            f32x4 acc[2] = {};
#pragma unroll
            for (int ks = 0; ks < 2; ++ks) {
                bf16x8 a = *(bf16x8*)&z2[(16 * w + lr) * LDZ + 32 * ks + lk * 8];
#pragma unroll
                for (int ct = 0; ct < 2; ++ct) {
                    bf16x8 b = *(const bf16x8*)&W3ft[k * 2048 + (16 * ct + lr) * 64 + 32 * ks + lk * 8];
                    acc[ct] = __builtin_amdgcn_mfma_f32_16x16x32_bf16(a, b, acc[ct], 0, 0, 0);
                }
            }
#pragma unroll
            for (int ct = 0; ct < 2; ++ct) {
                int c = 16 * ct + lr;
                if (c < 24) {
                    float bi = b3f[k * 24 + c];
#pragma unroll
                    for (int j = 0; j < 4; ++j) {
                        int r = 16 * w + lk * 4 + j, n = n0 + r;
                        if (n < N_NODES)
                            out[(size_t)n * OUT_F + 6 + 24 * k + c] =
                                1.f / (1.f + expf(-(acc[ct][j] + bi)));
                    }
                }
            }
        }
        // next iteration's z1 write is guarded by its own post-G1 sync
    }
}

extern "C" void kernel_launch(void* const* d_in, const int* in_sizes, int n_in,
                              void* d_out, int out_size, void* d_ws, size_t ws_size,
                              hipStream_t stream) {
    const float* x = (const float*)d_in[0];
    const int* ei = (const int*)d_in[1];
    const float* W1l = (const float*)d_in[2];
    const float* W1r = (const float*)d_in[3];
    const float* b1 = (const float*)d_in[4];
    const float* bn1_g = (const float*)d_in[5];
    const float* bn1_b = (const float*)d_in[6];
    const float* bn1_m = (const float*)d_in[7];
    const float* bn1_v = (const float*)d_in[8];
    const float* W2l = (const float*)d_in[9];
    const float* W2r = (const float*)d_in[10];
    const float* b2 = (const float*)d_in[11];
    const float* bn2_g = (const float*)d_in[12];
    const float* bn2_b = (const float*)d_in[13];
    const float* bn2_m = (const float*)d_in[14];
    const float* bn2_v = (const float*)d_in[15];
    const float* cnt_W1 = (const float*)d_in[16];
    const float* cnt_b1 = (const float*)d_in[17];
    const float* cnt_bn_g = (const float*)d_in[18];
    const float* cnt_bn_b = (const float*)d_in[19];
    const float* cnt_bn_m = (const float*)d_in[20];
    const float* cnt_bn_v = (const float*)d_in[21];
    const float* cnt_W2 = (const float*)d_in[22];
    const float* cnt_b2 = (const float*)d_in[23];
    const float* ch_W1 = (const float*)d_in[24];
    const float* ch_b1 = (const float*)d_in[25];
    const float* ch_bn1_g = (const float*)d_in[26];
    const float* ch_bn1_b = (const float*)d_in[27];
    const float* ch_bn1_m = (const float*)d_in[28];
    const float* ch_bn1_v = (const float*)d_in[29];
    const float* ch_W2 = (const float*)d_in[30];
    const float* ch_b2 = (const float*)d_in[31];
    const float* ch_bn2_g = (const float*)d_in[32];
    const float* ch_bn2_b = (const float*)d_in[33];
    const float* ch_bn2_m = (const float*)d_in[34];
    const float* ch_bn2_v = (const float*)d_in[35];
    const float* ch_W3 = (const float*)d_in[36];
    const float* ch_b3 = (const float*)d_in[37];

    float* out = (float*)d_out;

    int* cnt = (int*)d_ws;
    int* dbins = cnt + N_NODES;
    int* dcur = dbins + 64;
    int* rowstart = dcur + 64;
    int* cursor = rowstart + N_NODES;
    int* blocksums = cursor + N_NODES;
    int* perm = blocksums + 512;
    int* sorted_src = perm + N_NODES;
    short* h1b = (short*)(sorted_src + N_EDGES);
    short* hb = h1b + (size_t)N_NODES * H;
    short* W1t = hb + (size_t)N_NODES * H;
    short* W2ft = W1t + 98304;
    short* W3ft = W2ft + 49152;
    short* cntW1t = W3ft + 12288;
    short* cntW2ft = cntW1t + 8192;
    float* b2f = (float*)(cntW2ft + 1024);
    float* b3f = b2f + 384;
    float* cntb2f = b3f + 144;

    hipMemsetAsync(cnt, 0, (N_NODES + 64) * sizeof(int), stream);

    k_prep<<<663, 256, 0, stream>>>(ch_W1, ch_W2, ch_W3,
                                    ch_bn1_g, ch_bn1_b, ch_bn1_m, ch_bn1_v,
                                    ch_bn2_g, ch_bn2_b, ch_bn2_m, ch_bn2_v,
                                    cnt_W1, cnt_W2,
                                    cnt_bn_g, cnt_bn_b, cnt_bn_m, cnt_bn_v,
                                    ch_b2, ch_b3, cnt_b2,
                                    W1t, W2ft, W3ft, cntW1t, cntW2ft,
                                    b2f, b3f, cntb2f);

    k_hist<<<N_EDGES / 256, 256, 0, stream>>>(ei, cnt);
    k_scan1<<<SCAN_BLOCKS, 256, 0, stream>>>(cnt, rowstart, blocksums);
    k_scan2<<<1, 512, 0, stream>>>(blocksums);
    k_scan3<<<SCAN_BLOCKS, 256, 0, stream>>>(rowstart, blocksums, cursor);
    k_fill<<<N_EDGES / 256, 256, 0, stream>>>(ei, cursor, sorted_src);

    k_deghist<<<SCAN_BLOCKS, 256, 0, stream>>>(cnt, dbins);
    k_degscan<<<1, 64, 0, stream>>>(dbins, dcur);
    k_degscatter<<<SCAN_BLOCKS, 256, 0, stream>>>(cnt, dcur, perm);

    k_agg1_layer1<<<N_NODES / 4, 256, 0, stream>>>(x, rowstart, cnt, sorted_src, perm,
                                                   W1l, W1r, b1,
                                                   bn1_g, bn1_b, bn1_m, bn1_v, h1b);
    k_agg2_layer2<<<N_NODES / 32, 256, 0, stream>>>(h1b, rowstart, cnt, sorted_src, perm,
                                                    W2l, W2r, b2,
                                                    bn2_g, bn2_b, bn2_m, bn2_v, hb);
    k_heads_mfma<<<(N_NODES + 63) / 64, 256, 0, stream>>>(
        hb, cnt_b1, ch_b1, W1t, W2ft, W3ft, cntW1t, cntW2ft,
        b2f, b3f, cntb2f, out);
}

// Round 7
// 625.057 us; speedup vs baseline: 1.4153x; 1.3072x over previous
//
#include <hip/hip_runtime.h>

#define N_NODES 100000
#define N_EDGES 1600000
#define F_IN 17
#define H 128
#define K_TYPES 6
#define MD 12
#define OUT_F 150
#define EPSL 1e-5f

#define SCAN_BLOCKS 391  // ceil(100000/256)

#define LDH 136  // LDS row stride (bf16) for 128-col tiles
#define LDZ 72   // LDS row stride (bf16) for 64-col tiles

typedef __attribute__((ext_vector_type(8))) short bf16x8;
typedef __attribute__((ext_vector_type(4))) float f32x4;
typedef __attribute__((ext_vector_type(4))) short s16x4;

static __device__ __forceinline__ short f2bf(float f) {
    union { float f; unsigned u; } v;
    v.f = f;
    unsigned r = (v.u + 0x7FFF + ((v.u >> 16) & 1)) >> 16;  // RNE
    return (short)r;
}

// unpack int4 = 8 bf16 and accumulate into acc[0..7]
static __device__ __forceinline__ void acc8(float* a, int4 u) {
    union { unsigned u; float f; } lo, hi;
    lo.u = ((unsigned)u.x) << 16; hi.u = ((unsigned)u.x) & 0xFFFF0000u; a[0] += lo.f; a[1] += hi.f;
    lo.u = ((unsigned)u.y) << 16; hi.u = ((unsigned)u.y) & 0xFFFF0000u; a[2] += lo.f; a[3] += hi.f;
    lo.u = ((unsigned)u.z) << 16; hi.u = ((unsigned)u.z) & 0xFFFF0000u; a[4] += lo.f; a[5] += hi.f;
    lo.u = ((unsigned)u.w) << 16; hi.u = ((unsigned)u.w) & 0xFFFF0000u; a[6] += lo.f; a[7] += hi.f;
}

// ---------- CSR build: histogram ----------
__global__ __launch_bounds__(256) void k_hist(const int* __restrict__ ei,
                                              int* __restrict__ cnt) {
    int e = blockIdx.x * 256 + threadIdx.x;
    int dst = ei[N_EDGES + e];
    atomicAdd(&cnt[dst], 1);
}

// ---------- CSR build: scan stage 1 ----------
__global__ __launch_bounds__(256) void k_scan1(const int* __restrict__ cnt,
                                               int* __restrict__ rowstart,
                                               int* __restrict__ blocksums) {
    __shared__ int s[256];
    int tid = threadIdx.x;
    int i = blockIdx.x * 256 + tid;
    int v = (i < N_NODES) ? cnt[i] : 0;
    s[tid] = v;
    __syncthreads();
    for (int off = 1; off < 256; off <<= 1) {
        int t = (tid >= off) ? s[tid - off] : 0;
        __syncthreads();
        s[tid] += t;
        __syncthreads();
    }
    if (i < N_NODES) rowstart[i] = s[tid] - v;
    if (tid == 255) blocksums[blockIdx.x] = s[255];
}

// ---------- CSR build: scan stage 2 ----------
__global__ __launch_bounds__(512) void k_scan2(int* __restrict__ blocksums) {
    __shared__ int s[512];
    int t = threadIdx.x;
    int v0 = (t < SCAN_BLOCKS) ? blocksums[t] : 0;
    s[t] = v0;
    __syncthreads();
    for (int off = 1; off < 512; off <<= 1) {
        int tv = (t >= off) ? s[t - off] : 0;
        __syncthreads();
        s[t] += tv;
        __syncthreads();
    }
    if (t < SCAN_BLOCKS) blocksums[t] = s[t] - v0;
}

// ---------- CSR build: scan stage 3 ----------
__global__ __launch_bounds__(256) void k_scan3(int* __restrict__ rowstart,
                                               const int* __restrict__ blocksums,
                                               int* __restrict__ cursor) {
    int i = blockIdx.x * 256 + threadIdx.x;
    if (i < N_NODES) {
        int r = rowstart[i] + blocksums[blockIdx.x];
        rowstart[i] = r;
        cursor[i] = r;
    }
}

// ---------- CSR build: fill ----------
__global__ __launch_bounds__(256) void k_fill(const int* __restrict__ ei,
                                              int* __restrict__ cursor,
                                              int* __restrict__ sorted_src) {
    int e = blockIdx.x * 256 + threadIdx.x;
    int src = ei[e];
    int dst = ei[N_EDGES + e];
    int pos = atomicAdd(&cursor[dst], 1);
    sorted_src[pos] = src;
}

// ---------- degree sort: global histogram over clamped degree ----------
__global__ __launch_bounds__(256) void k_deghist(const int* __restrict__ cnt,
                                                 int* __restrict__ dbins) {
    __shared__ int lb[64];
    int t = threadIdx.x;
    if (t < 64) lb[t] = 0;
    __syncthreads();
    int i = blockIdx.x * 256 + t;
    if (i < N_NODES) {
        int d = cnt[i]; if (d > 63) d = 63;
        atomicAdd(&lb[d], 1);
    }
    __syncthreads();
    if (t < 64 && lb[t] > 0) atomicAdd(&dbins[t], lb[t]);
}

// ---------- degree sort: exclusive scan of 64 bins ----------
__global__ __launch_bounds__(64) void k_degscan(const int* __restrict__ dbins,
                                                int* __restrict__ dcur) {
    __shared__ int s[64];
    int t = threadIdx.x;
    int v = dbins[t];
    s[t] = v;
    __syncthreads();
    for (int off = 1; off < 64; off <<= 1) {
        int tv = (t >= off) ? s[t - off] : 0;
        __syncthreads();
        s[t] += tv;
        __syncthreads();
    }
    dcur[t] = s[t] - v;
}

// ---------- degree sort: block-chunked scatter (contention-free) ----------
__global__ __launch_bounds__(256) void k_degscatter(const int* __restrict__ cnt,
                                                    int* __restrict__ dcur,
                                                    int* __restrict__ perm) {
    __shared__ int lb[64];
    __shared__ int lbase[64];
    int t = threadIdx.x;
    if (t < 64) lb[t] = 0;
    __syncthreads();
    int i = blockIdx.x * 256 + t;
    int d = 0, lrank = 0;
    bool act = (i < N_NODES);
    if (act) {
        d = cnt[i]; if (d > 63) d = 63;
        lrank = atomicAdd(&lb[d], 1);  // LDS atomic: cheap
    }
    __syncthreads();
    if (t < 64 && lb[t] > 0) lbase[t] = atomicAdd(&dcur[t], lb[t]);  // 1 per (block,bin)
    __syncthreads();
    if (act) perm[lbase[d] + lrank] = i;
}

// ---------- prep: BN-fold + transpose + bf16-convert head weights ----------
__global__ __launch_bounds__(256) void k_prep(
    const float* __restrict__ ch_W1, const float* __restrict__ ch_W2,
    const float* __restrict__ ch_W3,
    const float* __restrict__ c1g, const float* __restrict__ c1b,
    const float* __restrict__ c1m, const float* __restrict__ c1v,
    const float* __restrict__ c2g, const float* __restrict__ c2b,
    const float* __restrict__ c2m, const float* __restrict__ c2v,
    const float* __restrict__ cnt_W1, const float* __restrict__ cnt_W2,
    const float* __restrict__ cbg, const float* __restrict__ cbb,
    const float* __restrict__ cbm, const float* __restrict__ cbv,
    const float* __restrict__ ch_b2, const float* __restrict__ ch_b3,
    const float* __restrict__ cnt_b2,
    short* __restrict__ W1t, short* __restrict__ W2ft, short* __restrict__ W3ft,
    short* __restrict__ cntW1t, short* __restrict__ cntW2ft,
    float* __restrict__ b2f, float* __restrict__ b3f, float* __restrict__ cntb2f) {
    int i = blockIdx.x * 256 + threadIdx.x;
    if (i < 98304) {  // W1t[k][o<128][d<128] <- ch_W1[k][d][o]
        int k = i >> 14, rem = i & 16383, o = rem >> 7, d = rem & 127;
        W1t[i] = f2bf(ch_W1[(k << 14) + (d << 7) + o]);
    } else if ((i -= 98304) < 49152) {  // W2ft[k][o<64][d<128] = A1[k][d]*ch_W2[k][d][o]
        int k = i >> 13, rem = i & 8191, o = rem >> 7, d = rem & 127;
        int ci = (k << 7) + d;
        float A1 = c1g[ci] * rsqrtf(c1v[ci] + EPSL);
        W2ft[i] = f2bf(ch_W2[(k << 13) + (d << 6) + o] * A1);
    } else if ((i -= 49152) < 12288) {  // W3ft[k][o<32][d<64], zero-pad o>=24
        int k = i >> 11, rem = i & 2047, o = rem >> 6, d = rem & 63;
        float val = 0.f;
        if (o < 24) {
            int ci = (k << 6) + d;
            float A2 = c2g[ci] * rsqrtf(c2v[ci] + EPSL);
            val = ch_W3[k * 1536 + d * 24 + o] * A2;
        }
        W3ft[i] = f2bf(val);
    } else if ((i -= 12288) < 8192) {  // cntW1t[o<64][d<128]
        int o = i >> 7, d = i & 127;
        cntW1t[i] = f2bf(cnt_W1[(d << 6) + o]);
    } else if ((i -= 8192) < 1024) {  // cntW2ft[o<16][d<64], zero-pad o>=6
        int o = i >> 6, d = i & 63;
        float val = 0.f;
        if (o < 6) val = cnt_W2[d * 6 + o] * (cbg[d] * rsqrtf(cbv[d] + EPSL));
        cntW2ft[i] = f2bf(val);
    } else if ((i -= 1024) < 384) {  // b2f[k][o<64]
        int k = i >> 6, o = i & 63;
        float s = ch_b2[i];
        for (int d = 0; d < 128; ++d) {
            int ci = (k << 7) + d;
            float A1 = c1g[ci] * rsqrtf(c1v[ci] + EPSL);
            float B1 = c1b[ci] - c1m[ci] * A1;
            s += B1 * ch_W2[(k << 13) + (d << 6) + o];
        }
        b2f[i] = s;
    } else if ((i -= 384) < 144) {  // b3f[k][o<24]
        int k = i / 24, o = i - k * 24;
        float s = ch_b3[i];
        for (int d = 0; d < 64; ++d) {
            int ci = (k << 6) + d;
            float A2 = c2g[ci] * rsqrtf(c2v[ci] + EPSL);
            float B2 = c2b[ci] - c2m[ci] * A2;
            s += B2 * ch_W3[k * 1536 + d * 24 + o];
        }
        b3f[i] = s;
    } else if ((i -= 144) < 6) {  // cntb2f[o<6]
        float s = cnt_b2[i];
        for (int d = 0; d < 64; ++d) {
            float Ac = cbg[d] * rsqrtf(cbv[d] + EPSL);
            float Bc = cbb[d] - cbm[d] * Ac;
            s += Bc * cnt_W2[d * 6 + i];
        }
        cntb2f[i] = s;
    }
}

// ---------- fused agg1 + layer1 (perm-balanced, unroll-4 gather, bf16 out) ----------
__global__ __launch_bounds__(256) void k_agg1_layer1(
    const float* __restrict__ x, const int* __restrict__ rowstart,
    const int* __restrict__ cnt, const int* __restrict__ sorted_src,
    const int* __restrict__ perm,
    const float* __restrict__ W1l, const float* __restrict__ W1r,
    const float* __restrict__ b1,
    const float* __restrict__ g, const float* __restrict__ bb,
    const float* __restrict__ m, const float* __restrict__ v,
    short* __restrict__ h1b) {
    int wave = threadIdx.x >> 6;
    int lane = threadIdx.x & 63;
    int n = perm[blockIdx.x * 4 + wave];
    __shared__ float as[4][F_IN], xs4[4][F_IN];

    int rs = rowstart[n];
    int d = cnt[n];
    if (lane < F_IN) {
        float acc = 0.f;
        int j = 0;
        for (; j + 4 <= d; j += 4) {
            int s0 = sorted_src[rs + j], s1 = sorted_src[rs + j + 1];
            int s2 = sorted_src[rs + j + 2], s3 = sorted_src[rs + j + 3];
            float a0 = x[(size_t)s0 * F_IN + lane];
            float a1 = x[(size_t)s1 * F_IN + lane];
            float a2 = x[(size_t)s2 * F_IN + lane];
            float a3 = x[(size_t)s3 * F_IN + lane];
            acc += (a0 + a1) + (a2 + a3);
        }
        for (; j < d; ++j) acc += x[(size_t)sorted_src[rs + j] * F_IN + lane];
        float inv = 1.0f / fmaxf((float)d, 1.0f);
        as[wave][lane] = acc * inv;
        xs4[wave][lane] = x[(size_t)n * F_IN + lane];
    }
    __syncthreads();

    float a0 = b1[lane], a1 = b1[lane + 64];
    for (int i = 0; i < F_IN; ++i) {
        float av = as[wave][i], xv = xs4[wave][i];
        a0 += av * W1l[i * H + lane] + xv * W1r[i * H + lane];
        a1 += av * W1l[i * H + 64 + lane] + xv * W1r[i * H + 64 + lane];
    }
    int f0 = lane, f1 = lane + 64;
    float y0 = (a0 - m[f0]) * rsqrtf(v[f0] + EPSL) * g[f0] + bb[f0];
    float y1 = (a1 - m[f1]) * rsqrtf(v[f1] + EPSL) * g[f1] + bb[f1];
    h1b[(size_t)n * H + f0] = f2bf(fmaxf(y0, 0.f));
    h1b[(size_t)n * H + f1] = f2bf(fmaxf(y1, 0.f));
}

// ---------- fused agg2 + layer2 v3: bf16 gather (quarter-wave/node) + fp32 reg-tiled GEMM ----------
__global__ __launch_bounds__(256) void k_agg2_layer2(
    const short* __restrict__ h1b, const int* __restrict__ rowstart,
    const int* __restrict__ cnt, const int* __restrict__ sorted_src,
    const int* __restrict__ perm,
    const float* __restrict__ W2l, const float* __restrict__ W2r,
    const float* __restrict__ b2,
    const float* __restrict__ g, const float* __restrict__ bb,
    const float* __restrict__ m, const float* __restrict__ v,
    short* __restrict__ hb) {
    __shared__ float xs[32][256];  // [r][0:128]=agg_mean, [r][128:256]=root h1
    __shared__ int nid[32];
    int t = threadIdx.x;
    int wave = t >> 6, lane = t & 63;
    int q4 = lane >> 4;
    int li = lane & 15;
    int n0 = blockIdx.x * 32;

    for (int gq = 0; gq < 2; ++gq) {
        int r = wave * 8 + gq * 4 + q4;
        int n = perm[n0 + r];
        if (li == 0) nid[r] = n;
        int rs = rowstart[n];
        int d = cnt[n];
        float acc[8] = {0.f, 0.f, 0.f, 0.f, 0.f, 0.f, 0.f, 0.f};
        for (int j = 0; j < d; j += 4) {
            int rem = d - j;
            int4 v0 = *(const int4*)&h1b[(size_t)sorted_src[rs + j] * H + li * 8];
            int4 v1 = {0, 0, 0, 0}, v2 = {0, 0, 0, 0}, v3 = {0, 0, 0, 0};
            if (rem > 1) v1 = *(const int4*)&h1b[(size_t)sorted_src[rs + j + 1] * H + li * 8];
            if (rem > 2) v2 = *(const int4*)&h1b[(size_t)sorted_src[rs + j + 2] * H + li * 8];
            if (rem > 3) v3 = *(const int4*)&h1b[(size_t)sorted_src[rs + j + 3] * H + li * 8];
            acc8(acc, v0); acc8(acc, v1); acc8(acc, v2); acc8(acc, v3);
        }
        float inv = 1.f / fmaxf((float)d, 1.f);
        float4 w0 = {acc[0] * inv, acc[1] * inv, acc[2] * inv, acc[3] * inv};
        float4 w1 = {acc[4] * inv, acc[5] * inv, acc[6] * inv, acc[7] * inv};
        *(float4*)&xs[r][8 * li] = w0;
        *(float4*)&xs[r][8 * li + 4] = w1;
        float rt[8] = {0.f, 0.f, 0.f, 0.f, 0.f, 0.f, 0.f, 0.f};
        int4 rv = *(const int4*)&h1b[(size_t)n * H + li * 8];
        acc8(rt, rv);
        *(float4*)&xs[r][128 + 8 * li] = *(float4*)&rt[0];
        *(float4*)&xs[r][128 + 8 * li + 4] = *(float4*)&rt[4];
    }
    __syncthreads();

    int cg = t & 31;
    int rg = t >> 5;
    float4 acc2[4] = {};
    for (int k = 0; k < H; ++k) {
        float4 wl = *(const float4*)&W2l[k * H + 4 * cg];
        float4 wr = *(const float4*)&W2r[k * H + 4 * cg];
#pragma unroll
        for (int i = 0; i < 4; ++i) {
            float a = xs[4 * rg + i][k];
            float b = xs[4 * rg + i][128 + k];
            acc2[i].x += a * wl.x + b * wr.x;
            acc2[i].y += a * wl.y + b * wr.y;
            acc2[i].z += a * wl.z + b * wr.z;
            acc2[i].w += a * wl.w + b * wr.w;
        }
    }
    int c0 = 4 * cg;
    float4 bi = *(const float4*)&b2[c0];
    float4 vv = *(const float4*)&v[c0];
    float4 gg = *(const float4*)&g[c0];
    float4 mm = *(const float4*)&m[c0];
    float4 be = *(const float4*)&bb[c0];
    float scx = rsqrtf(vv.x + EPSL) * gg.x;
    float scy = rsqrtf(vv.y + EPSL) * gg.y;
    float scz = rsqrtf(vv.z + EPSL) * gg.z;
    float scw = rsqrtf(vv.w + EPSL) * gg.w;
#pragma unroll
    for (int i = 0; i < 4; ++i) {
        int n = nid[4 * rg + i];
        s16x4 o;
        o.x = f2bf(fmaxf((acc2[i].x + bi.x - mm.x) * scx + be.x, 0.f));
        o.y = f2bf(fmaxf((acc2[i].y + bi.y - mm.y) * scy + be.y, 0.f));
        o.z = f2bf(fmaxf((acc2[i].z + bi.z - mm.z) * scz + be.z, 0.f));
        o.w = f2bf(fmaxf((acc2[i].w + bi.w - mm.w) * scw + be.w, 0.f));
        *(s16x4*)&hb[(size_t)n * H + c0] = o;
    }
}

// ---------- heads via MFMA v3: wave-owns-columns, B in registers (batched loads) ----------
// Wave roles per stage:
//  G1 (64x128,K=128): wave w -> cols [32w,32w+32), all 64 rows. 8 B-loads, 32 MFMA.
//  G2-shape (64x64,K=128): rh=w>>1 rows [32rh..), ch=w&1 cols [32ch..). 8 B-loads, 16 MFMA.
//  G3 (64x32,K=64): rows [32rh..), cols [16ch..). 2 B-loads, 4 MFMA.
__global__ __launch_bounds__(256) void k_heads_mfma(
    const short* __restrict__ hb,
    const float* __restrict__ cntb1, const float* __restrict__ ch_b1,
    const short* __restrict__ W1t, const short* __restrict__ W2ft,
    const short* __restrict__ W3ft, const short* __restrict__ cntW1t,
    const short* __restrict__ cntW2ft,
    const float* __restrict__ b2f, const float* __restrict__ b3f,
    const float* __restrict__ cntb2f,
    float* __restrict__ out) {
    __shared__ short hs[64 * LDH];
    __shared__ short z1[64 * LDH];
    __shared__ short z2[64 * LDZ];

    int t = threadIdx.x;
    int lane = t & 63, w = t >> 6;
    int lr = lane & 15, lk = lane >> 4;
    int rh = w >> 1, ch = w & 1;
    int n0 = blockIdx.x * 64;

#pragma unroll
    for (int it = 0; it < 4; ++it) {
        int idx = t * 8 + it * 2048;
        int r = idx >> 7, c = idx & 127;
        int n = n0 + r;
        if (n > N_NODES - 1) n = N_NODES - 1;
        *(int4*)&hs[r * LDH + c] = *(const int4*)&hb[(size_t)n * 128 + c];
    }
    __syncthreads();

    // ===== count head G1: hs(64x128) @ cntW1t^T -> z2(64x64) =====
    {
        bf16x8 Bv[2][4];
#pragma unroll
        for (int cc = 0; cc < 2; ++cc)
#pragma unroll
            for (int ks = 0; ks < 4; ++ks)
                Bv[cc][ks] = *(const bf16x8*)&cntW1t[(32 * ch + 16 * cc + lr) * 128 + 32 * ks + 8 * lk];
        f32x4 acc[2][2] = {};
#pragma unroll
        for (int ks = 0; ks < 4; ++ks) {
            bf16x8 a0 = *(bf16x8*)&hs[(32 * rh + lr) * LDH + 32 * ks + 8 * lk];
            bf16x8 a1 = *(bf16x8*)&hs[(32 * rh + 16 + lr) * LDH + 32 * ks + 8 * lk];
#pragma unroll
            for (int cc = 0; cc < 2; ++cc) {
                acc[0][cc] = __builtin_amdgcn_mfma_f32_16x16x32_bf16(a0, Bv[cc][ks], acc[0][cc], 0, 0, 0);
                acc[1][cc] = __builtin_amdgcn_mfma_f32_16x16x32_bf16(a1, Bv[cc][ks], acc[1][cc], 0, 0, 0);
            }
        }
#pragma unroll
        for (int rr = 0; rr < 2; ++rr)
#pragma unroll
            for (int cc = 0; cc < 2; ++cc) {
                int c = 32 * ch + 16 * cc + lr;
                float bi = cntb1[c];
#pragma unroll
                for (int j = 0; j < 4; ++j) {
                    int r = 32 * rh + 16 * rr + 4 * lk + j;
                    z2[r * LDZ + c] = f2bf(fmaxf(acc[rr][cc][j] + bi, 0.f));
                }
            }
    }
    __syncthreads();
    // ===== count head G2: z2 @ cntW2ft^T -> out[:,0:6]; wave w rows [16w..) =====
    {
        f32x4 acc = {};
#pragma unroll
        for (int ks = 0; ks < 2; ++ks) {
            bf16x8 b = *(const bf16x8*)&cntW2ft[lr * 64 + 32 * ks + 8 * lk];
            bf16x8 a = *(bf16x8*)&z2[(16 * w + lr) * LDZ + 32 * ks + 8 * lk];
            acc = __builtin_amdgcn_mfma_f32_16x16x32_bf16(a, b, acc, 0, 0, 0);
        }
        if (lr < 6) {
            float bi = cntb2f[lr];
#pragma unroll
            for (int j = 0; j < 4; ++j) {
                int r = 16 * w + 4 * lk + j, n = n0 + r;
                if (n < N_NODES) out[(size_t)n * OUT_F + lr] = acc[j] + bi;
            }
        }
    }
    // no barrier: next stage writes z1 only; z2 WAR is fenced by the barrier after coord G1

    // ===== coord heads =====
    for (int k = 0; k < K_TYPES; ++k) {
        const short* W1k = W1t + k * 16384;
        // G1: hs @ W1k^T -> z1(64x128); wave w owns cols [32w,32w+32), sweeps 64 rows
        {
            bf16x8 Bv[2][4];
#pragma unroll
            for (int cc = 0; cc < 2; ++cc)
#pragma unroll
                for (int ks = 0; ks < 4; ++ks)
                    Bv[cc][ks] = *(const bf16x8*)&W1k[(32 * w + 16 * cc + lr) * 128 + 32 * ks + 8 * lk];
            f32x4 acc[4][2] = {};
#pragma unroll
            for (int ks = 0; ks < 4; ++ks) {
                bf16x8 a0 = *(bf16x8*)&hs[(lr) * LDH + 32 * ks + 8 * lk];
                bf16x8 a1 = *(bf16x8*)&hs[(16 + lr) * LDH + 32 * ks + 8 * lk];
                bf16x8 a2 = *(bf16x8*)&hs[(32 + lr) * LDH + 32 * ks + 8 * lk];
                bf16x8 a3 = *(bf16x8*)&hs[(48 + lr) * LDH + 32 * ks + 8 * lk];
#pragma unroll
                for (int cc = 0; cc < 2; ++cc) {
                    acc[0][cc] = __builtin_amdgcn_mfma_f32_16x16x32_bf16(a0, Bv[cc][ks], acc[0][cc], 0, 0, 0);
                    acc[1][cc] = __builtin_amdgcn_mfma_f32_16x16x32_bf16(a1, Bv[cc][ks], acc[1][cc], 0, 0, 0);
                    acc[2][cc] = __builtin_amdgcn_mfma_f32_16x16x32_bf16(a2, Bv[cc][ks], acc[2][cc], 0, 0, 0);
                    acc[3][cc] = __builtin_amdgcn_mfma_f32_16x16x32_bf16(a3, Bv[cc][ks], acc[3][cc], 0, 0, 0);
                }
            }
#pragma unroll
            for (int rt = 0; rt < 4; ++rt)
#pragma unroll
                for (int cc = 0; cc < 2; ++cc) {
                    int c = 32 * w + 16 * cc + lr;
                    float bi = ch_b1[k * 128 + c];
#pragma unroll
                    for (int j = 0; j < 4; ++j) {
                        int r = 16 * rt + 4 * lk + j;
                        z1[r * LDH + c] = f2bf(fmaxf(acc[rt][cc][j] + bi, 0.f));
                    }
                }
        }
        __syncthreads();  // z1 ready; also fences z2 WAR (prev readers done)
        // G2: z1 @ W2ft^T -> z2(64x64); wave (rh,ch)
        {
            const short* W2k = W2ft + k * 8192;
            bf16x8 Bv[2][4];
#pragma unroll
            for (int cc = 0; cc < 2; ++cc)
#pragma unroll
                for (int ks = 0; ks < 4; ++ks)
                    Bv[cc][ks] = *(const bf16x8*)&W2k[(32 * ch + 16 * cc + lr) * 128 + 32 * ks + 8 * lk];
            f32x4 acc[2][2] = {};
#pragma unroll
            for (int ks = 0; ks < 4; ++ks) {
                bf16x8 a0 = *(bf16x8*)&z1[(32 * rh + lr) * LDH + 32 * ks + 8 * lk];
                bf16x8 a1 = *(bf16x8*)&z1[(32 * rh + 16 + lr) * LDH + 32 * ks + 8 * lk];
#pragma unroll
                for (int cc = 0; cc < 2; ++cc) {
                    acc[0][cc] = __builtin_amdgcn_mfma_f32_16x16x32_bf16(a0, Bv[cc][ks], acc[0][cc], 0, 0, 0);
                    acc[1][cc] = __builtin_amdgcn_mfma_f32_16x16x32_bf16(a1, Bv[cc][ks], acc[1][cc], 0, 0, 0);
                }
            }
#pragma unroll
            for (int rr = 0; rr < 2; ++rr)
#pragma unroll
                for (int cc = 0; cc < 2; ++cc) {
                    int c = 32 * ch + 16 * cc + lr;
                    float bi = b2f[k * 64 + c];
#pragma unroll
                    for (int j = 0; j < 4; ++j) {
                        int r = 32 * rh + 16 * rr + 4 * lk + j;
                        z2[r * LDZ + c] = f2bf(fmaxf(acc[rr][cc][j] + bi, 0.f));
                    }
                }
        }
        __syncthreads();  // z2 ready
        // G3: z2 @ W3ft^T -> sigmoid -> out; wave (rh,ch): rows [32rh..), cols [16ch..)
        {
            const short* W3k = W3ft + k * 2048;
            bf16x8 Bv2[2];
#pragma unroll
            for (int ks = 0; ks < 2; ++ks)
                Bv2[ks] = *(const bf16x8*)&W3k[(16 * ch + lr) * 64 + 32 * ks + 8 * lk];
            f32x4 acc[2] = {};
#pragma unroll
            for (int ks = 0; ks < 2; ++ks) {
                bf16x8 a0 = *(bf16x8*)&z2[(32 * rh + lr) * LDZ + 32 * ks + 8 * lk];
                bf16x8 a1 = *(bf16x8*)&z2[(32 * rh + 16 + lr) * LDZ + 32 * ks + 8 * lk];
                acc[0] = __builtin_amdgcn_mfma_f32_16x16x32_bf16(a0, Bv2[ks], acc[0], 0, 0, 0);
                acc[1] = __builtin_amdgcn_mfma_f32_16x16x32_bf16(a1, Bv2[ks], acc[1], 0, 0, 0);
            }
            int c = 16 * ch + lr;
            if (c < 24) {
                float bi = b3f[k * 24 + c];
#pragma unroll
                for (int rr = 0; rr < 2; ++rr)
#pragma unroll
                    for (int j = 0; j < 4; ++j) {
                        int r = 32 * rh + 16 * rr + 4 * lk + j, n = n0 + r;
                        if (n < N_NODES)
                            out[(size_t)n * OUT_F + 6 + 24 * k + c] =
                                1.f / (1.f + expf(-(acc[rr][j] + bi)));
                    }
            }
        }
        // no barrier: next G1 writes z1 (readers fenced above); z2 WAR fenced by barrier after next G1
    }
}

extern "C" void kernel_launch(void* const* d_in, const int* in_sizes, int n_in,
                              void* d_out, int out_size, void* d_ws, size_t ws_size,
                              hipStream_t stream) {
    const float* x = (const float*)d_in[0];
    const int* ei = (const int*)d_in[1];
    const float* W1l = (const float*)d_in[2];
    const float* W1r = (const float*)d_in[3];
    const float* b1 = (const float*)d_in[4];
    const float* bn1_g = (const float*)d_in[5];
    const float* bn1_b = (const float*)d_in[6];
    const float* bn1_m = (const float*)d_in[7];
    const float* bn1_v = (const float*)d_in[8];
    const float* W2l = (const float*)d_in[9];
    const float* W2r = (const float*)d_in[10];
    const float* b2 = (const float*)d_in[11];
    const float* bn2_g = (const float*)d_in[12];
    const float* bn2_b = (const float*)d_in[13];
    const float* bn2_m = (const float*)d_in[14];
    const float* bn2_v = (const float*)d_in[15];
    const float* cnt_W1 = (const float*)d_in[16];
    const float* cnt_b1 = (const float*)d_in[17];
    const float* cnt_bn_g = (const float*)d_in[18];
    const float* cnt_bn_b = (const float*)d_in[19];
    const float* cnt_bn_m = (const float*)d_in[20];
    const float* cnt_bn_v = (const float*)d_in[21];
    const float* cnt_W2 = (const float*)d_in[22];
    const float* cnt_b2 = (const float*)d_in[23];
    const float* ch_W1 = (const float*)d_in[24];
    const float* ch_b1 = (const float*)d_in[25];
    const float* ch_bn1_g = (const float*)d_in[26];
    const float* ch_bn1_b = (const float*)d_in[27];
    const float* ch_bn1_m = (const float*)d_in[28];
    const float* ch_bn1_v = (const float*)d_in[29];
    const float* ch_W2 = (const float*)d_in[30];
    const float* ch_b2 = (const float*)d_in[31];
    const float* ch_bn2_g = (const float*)d_in[32];
    const float* ch_bn2_b = (const float*)d_in[33];
    const float* ch_bn2_m = (const float*)d_in[34];
    const float* ch_bn2_v = (const float*)d_in[35];
    const float* ch_W3 = (const float*)d_in[36];
    const float* ch_b3 = (const float*)d_in[37];

    float* out = (float*)d_out;

    int* cnt = (int*)d_ws;
    int* dbins = cnt + N_NODES;
    int* dcur = dbins + 64;
    int* rowstart = dcur + 64;
    int* cursor = rowstart + N_NODES;
    int* blocksums = cursor + N_NODES;
    int* perm = blocksums + 512;
    int* sorted_src = perm + N_NODES;
    short* h1b = (short*)(sorted_src + N_EDGES);
    short* hb = h1b + (size_t)N_NODES * H;
    short* W1t = hb + (size_t)N_NODES * H;
    short* W2ft = W1t + 98304;
    short* W3ft = W2ft + 49152;
    short* cntW1t = W3ft + 12288;
    short* cntW2ft = cntW1t + 8192;
    float* b2f = (float*)(cntW2ft + 1024);
    float* b3f = b2f + 384;
    float* cntb2f = b3f + 144;

    hipMemsetAsync(cnt, 0, (N_NODES + 64) * sizeof(int), stream);

    k_prep<<<663, 256, 0, stream>>>(ch_W1, ch_W2, ch_W3,
                                    ch_bn1_g, ch_bn1_b, ch_bn1_m, ch_bn1_v,
                                    ch_bn2_g, ch_bn2_b, ch_bn2_m, ch_bn2_v,
                                    cnt_W1, cnt_W2,
                                    cnt_bn_g, cnt_bn_b, cnt_bn_m, cnt_bn_v,
                                    ch_b2, ch_b3, cnt_b2,
                                    W1t, W2ft, W3ft, cntW1t, cntW2ft,
                                    b2f, b3f, cntb2f);

    k_hist<<<N_EDGES / 256, 256, 0, stream>>>(ei, cnt);
    k_scan1<<<SCAN_BLOCKS, 256, 0, stream>>>(cnt, rowstart, blocksums);
    k_scan2<<<1, 512, 0, stream>>>(blocksums);
    k_scan3<<<SCAN_BLOCKS, 256, 0, stream>>>(rowstart, blocksums, cursor);
    k_fill<<<N_EDGES / 256, 256, 0, stream>>>(ei, cursor, sorted_src);

    k_deghist<<<SCAN_BLOCKS, 256, 0, stream>>>(cnt, dbins);
    k_degscan<<<1, 64, 0, stream>>>(dbins, dcur);
    k_degscatter<<<SCAN_BLOCKS, 256, 0, stream>>>(cnt, dcur, perm);

    k_agg1_layer1<<<N_NODES / 4, 256, 0, stream>>>(x, rowstart, cnt, sorted_src, perm,
                                                   W1l, W1r, b1,
                                                   bn1_g, bn1_b, bn1_m, bn1_v, h1b);
    k_agg2_layer2<<<N_NODES / 32, 256, 0, stream>>>(h1b, rowstart, cnt, sorted_src, perm,
                                                    W2l, W2r, b2,
                                                    bn2_g, bn2_b, bn2_m, bn2_v, hb);
    k_heads_mfma<<<(N_NODES + 63) / 64, 256, 0, stream>>>(
        hb, cnt_b1, ch_b1, W1t, W2ft, W3ft, cntW1t, cntW2ft,
        b2f, b3f, cntb2f, out);
}

// Round 8
// 562.740 us; speedup vs baseline: 1.5721x; 1.1107x over previous
//
#include <hip/hip_runtime.h>

#define N_NODES 100000
#define N_EDGES 1600000
#define F_IN 17
#define H 128
#define K_TYPES 6
#define MD 12
#define OUT_F 150
#define EPSL 1e-5f

#define SCAN_BLOCKS 391  // ceil(100000/256)

#define LDH 136   // LDS row stride (bf16) for 128-col tiles
#define LDZ 72    // LDS row stride (bf16) for 64-col tiles
#define LDA2 264  // LDS row stride (bf16) for agg2's 256-col tile

typedef __attribute__((ext_vector_type(8))) short bf16x8;
typedef __attribute__((ext_vector_type(4))) float f32x4;
typedef __attribute__((ext_vector_type(4))) short s16x4;

static __device__ __forceinline__ short f2bf(float f) {
    union { float f; unsigned u; } v;
    v.f = f;
    unsigned r = (v.u + 0x7FFF + ((v.u >> 16) & 1)) >> 16;  // RNE
    return (short)r;
}

// unpack int4 = 8 bf16 and accumulate into acc[0..7]
static __device__ __forceinline__ void acc8(float* a, int4 u) {
    union { unsigned u; float f; } lo, hi;
    lo.u = ((unsigned)u.x) << 16; hi.u = ((unsigned)u.x) & 0xFFFF0000u; a[0] += lo.f; a[1] += hi.f;
    lo.u = ((unsigned)u.y) << 16; hi.u = ((unsigned)u.y) & 0xFFFF0000u; a[2] += lo.f; a[3] += hi.f;
    lo.u = ((unsigned)u.z) << 16; hi.u = ((unsigned)u.z) & 0xFFFF0000u; a[4] += lo.f; a[5] += hi.f;
    lo.u = ((unsigned)u.w) << 16; hi.u = ((unsigned)u.w) & 0xFFFF0000u; a[6] += lo.f; a[7] += hi.f;
}

// ---------- CSR build: histogram ----------
__global__ __launch_bounds__(256) void k_hist(const int* __restrict__ ei,
                                              int* __restrict__ cnt) {
    int e = blockIdx.x * 256 + threadIdx.x;
    int dst = ei[N_EDGES + e];
    atomicAdd(&cnt[dst], 1);
}

// ---------- CSR build: scan stage 1 ----------
__global__ __launch_bounds__(256) void k_scan1(const int* __restrict__ cnt,
                                               int* __restrict__ rowstart,
                                               int* __restrict__ blocksums) {
    __shared__ int s[256];
    int tid = threadIdx.x;
    int i = blockIdx.x * 256 + tid;
    int v = (i < N_NODES) ? cnt[i] : 0;
    s[tid] = v;
    __syncthreads();
    for (int off = 1; off < 256; off <<= 1) {
        int t = (tid >= off) ? s[tid - off] : 0;
        __syncthreads();
        s[tid] += t;
        __syncthreads();
    }
    if (i < N_NODES) rowstart[i] = s[tid] - v;
    if (tid == 255) blocksums[blockIdx.x] = s[255];
}

// ---------- CSR build: scan stage 2 ----------
__global__ __launch_bounds__(512) void k_scan2(int* __restrict__ blocksums) {
    __shared__ int s[512];
    int t = threadIdx.x;
    int v0 = (t < SCAN_BLOCKS) ? blocksums[t] : 0;
    s[t] = v0;
    __syncthreads();
    for (int off = 1; off < 512; off <<= 1) {
        int tv = (t >= off) ? s[t - off] : 0;
        __syncthreads();
        s[t] += tv;
        __syncthreads();
    }
    if (t < SCAN_BLOCKS) blocksums[t] = s[t] - v0;
}

// ---------- CSR build: scan stage 3 ----------
__global__ __launch_bounds__(256) void k_scan3(int* __restrict__ rowstart,
                                               const int* __restrict__ blocksums,
                                               int* __restrict__ cursor) {
    int i = blockIdx.x * 256 + threadIdx.x;
    if (i < N_NODES) {
        int r = rowstart[i] + blocksums[blockIdx.x];
        rowstart[i] = r;
        cursor[i] = r;
    }
}

// ---------- CSR build: fill ----------
__global__ __launch_bounds__(256) void k_fill(const int* __restrict__ ei,
                                              int* __restrict__ cursor,
                                              int* __restrict__ sorted_src) {
    int e = blockIdx.x * 256 + threadIdx.x;
    int src = ei[e];
    int dst = ei[N_EDGES + e];
    int pos = atomicAdd(&cursor[dst], 1);
    sorted_src[pos] = src;
}

// ---------- degree sort: global histogram over clamped degree ----------
__global__ __launch_bounds__(256) void k_deghist(const int* __restrict__ cnt,
                                                 int* __restrict__ dbins) {
    __shared__ int lb[64];
    int t = threadIdx.x;
    if (t < 64) lb[t] = 0;
    __syncthreads();
    int i = blockIdx.x * 256 + t;
    if (i < N_NODES) {
        int d = cnt[i]; if (d > 63) d = 63;
        atomicAdd(&lb[d], 1);
    }
    __syncthreads();
    if (t < 64 && lb[t] > 0) atomicAdd(&dbins[t], lb[t]);
}

// ---------- degree sort: exclusive scan of 64 bins ----------
__global__ __launch_bounds__(64) void k_degscan(const int* __restrict__ dbins,
                                                int* __restrict__ dcur) {
    __shared__ int s[64];
    int t = threadIdx.x;
    int v = dbins[t];
    s[t] = v;
    __syncthreads();
    for (int off = 1; off < 64; off <<= 1) {
        int tv = (t >= off) ? s[t - off] : 0;
        __syncthreads();
        s[t] += tv;
        __syncthreads();
    }
    dcur[t] = s[t] - v;
}

// ---------- degree sort: block-chunked scatter (contention-free) ----------
__global__ __launch_bounds__(256) void k_degscatter(const int* __restrict__ cnt,
                                                    int* __restrict__ dcur,
                                                    int* __restrict__ perm) {
    __shared__ int lb[64];
    __shared__ int lbase[64];
    int t = threadIdx.x;
    if (t < 64) lb[t] = 0;
    __syncthreads();
    int i = blockIdx.x * 256 + t;
    int d = 0, lrank = 0;
    bool act = (i < N_NODES);
    if (act) {
        d = cnt[i]; if (d > 63) d = 63;
        lrank = atomicAdd(&lb[d], 1);
    }
    __syncthreads();
    if (t < 64 && lb[t] > 0) lbase[t] = atomicAdd(&dcur[t], lb[t]);
    __syncthreads();
    if (act) perm[lbase[d] + lrank] = i;
}

// ---------- prep: BN-fold + transpose + bf16-convert weights ----------
__global__ __launch_bounds__(256) void k_prep(
    const float* __restrict__ ch_W1, const float* __restrict__ ch_W2,
    const float* __restrict__ ch_W3,
    const float* __restrict__ c1g, const float* __restrict__ c1b,
    const float* __restrict__ c1m, const float* __restrict__ c1v,
    const float* __restrict__ c2g, const float* __restrict__ c2b,
    const float* __restrict__ c2m, const float* __restrict__ c2v,
    const float* __restrict__ cnt_W1, const float* __restrict__ cnt_W2,
    const float* __restrict__ cbg, const float* __restrict__ cbb,
    const float* __restrict__ cbm, const float* __restrict__ cbv,
    const float* __restrict__ ch_b2, const float* __restrict__ ch_b3,
    const float* __restrict__ cnt_b2,
    const float* __restrict__ W2l, const float* __restrict__ W2r,
    short* __restrict__ W1t, short* __restrict__ W2ft, short* __restrict__ W3ft,
    short* __restrict__ cntW1t, short* __restrict__ cntW2ft,
    short* __restrict__ W2t,
    float* __restrict__ b2f, float* __restrict__ b3f, float* __restrict__ cntb2f) {
    int i = blockIdx.x * 256 + threadIdx.x;
    if (i < 98304) {  // W1t[k][o<128][d<128] <- ch_W1[k][d][o]
        int k = i >> 14, rem = i & 16383, o = rem >> 7, d = rem & 127;
        W1t[i] = f2bf(ch_W1[(k << 14) + (d << 7) + o]);
    } else if ((i -= 98304) < 49152) {  // W2ft[k][o<64][d<128] = A1[k][d]*ch_W2[k][d][o]
        int k = i >> 13, rem = i & 8191, o = rem >> 7, d = rem & 127;
        int ci = (k << 7) + d;
        float A1 = c1g[ci] * rsqrtf(c1v[ci] + EPSL);
        W2ft[i] = f2bf(ch_W2[(k << 13) + (d << 6) + o] * A1);
    } else if ((i -= 49152) < 12288) {  // W3ft[k][o<32][d<64], zero-pad o>=24
        int k = i >> 11, rem = i & 2047, o = rem >> 6, d = rem & 63;
        float val = 0.f;
        if (o < 24) {
            int ci = (k << 6) + d;
            float A2 = c2g[ci] * rsqrtf(c2v[ci] + EPSL);
            val = ch_W3[k * 1536 + d * 24 + o] * A2;
        }
        W3ft[i] = f2bf(val);
    } else if ((i -= 12288) < 8192) {  // cntW1t[o<64][d<128]
        int o = i >> 7, d = i & 127;
        cntW1t[i] = f2bf(cnt_W1[(d << 6) + o]);
    } else if ((i -= 8192) < 1024) {  // cntW2ft[o<16][d<64], zero-pad o>=6
        int o = i >> 6, d = i & 63;
        float val = 0.f;
        if (o < 6) val = cnt_W2[d * 6 + o] * (cbg[d] * rsqrtf(cbv[d] + EPSL));
        cntW2ft[i] = f2bf(val);
    } else if ((i -= 1024) < 384) {  // b2f[k][o<64]
        int k = i >> 6, o = i & 63;
        float s = ch_b2[i];
        for (int d = 0; d < 128; ++d) {
            int ci = (k << 7) + d;
            float A1 = c1g[ci] * rsqrtf(c1v[ci] + EPSL);
            float B1 = c1b[ci] - c1m[ci] * A1;
            s += B1 * ch_W2[(k << 13) + (d << 6) + o];
        }
        b2f[i] = s;
    } else if ((i -= 384) < 144) {  // b3f[k][o<24]
        int k = i / 24, o = i - k * 24;
        float s = ch_b3[i];
        for (int d = 0; d < 64; ++d) {
            int ci = (k << 6) + d;
            float A2 = c2g[ci] * rsqrtf(c2v[ci] + EPSL);
            float B2 = c2b[ci] - c2m[ci] * A2;
            s += B2 * ch_W3[k * 1536 + d * 24 + o];
        }
        b3f[i] = s;
    } else if ((i -= 144) < 6) {  // cntb2f[o<6]
        float s = cnt_b2[i];
        for (int d = 0; d < 64; ++d) {
            float Ac = cbg[d] * rsqrtf(cbv[d] + EPSL);
            float Bc = cbb[d] - cbm[d] * Ac;
            s += Bc * cnt_W2[d * 6 + i];
        }
        cntb2f[i] = s;
    } else if ((i -= 6) < 32768) {  // W2t[o<128][k<256]: k<128 -> W2l[k][o], else W2r[k-128][o]
        int o = i >> 8, k = i & 255;
        float val = (k < 128) ? W2l[k * 128 + o] : W2r[(k - 128) * 128 + o];
        W2t[i] = f2bf(val);
    }
}

// ---------- fused agg1 + layer1 (perm-balanced, unroll-4 gather, bf16 out) ----------
__global__ __launch_bounds__(256) void k_agg1_layer1(
    const float* __restrict__ x, const int* __restrict__ rowstart,
    const int* __restrict__ cnt, const int* __restrict__ sorted_src,
    const int* __restrict__ perm,
    const float* __restrict__ W1l, const float* __restrict__ W1r,
    const float* __restrict__ b1,
    const float* __restrict__ g, const float* __restrict__ bb,
    const float* __restrict__ m, const float* __restrict__ v,
    short* __restrict__ h1b) {
    int wave = threadIdx.x >> 6;
    int lane = threadIdx.x & 63;
    int n = perm[blockIdx.x * 4 + wave];
    __shared__ float as[4][F_IN], xs4[4][F_IN];

    int rs = rowstart[n];
    int d = cnt[n];
    if (lane < F_IN) {
        float acc = 0.f;
        int j = 0;
        for (; j + 4 <= d; j += 4) {
            int s0 = sorted_src[rs + j], s1 = sorted_src[rs + j + 1];
            int s2 = sorted_src[rs + j + 2], s3 = sorted_src[rs + j + 3];
            float a0 = x[(size_t)s0 * F_IN + lane];
            float a1 = x[(size_t)s1 * F_IN + lane];
            float a2 = x[(size_t)s2 * F_IN + lane];
            float a3 = x[(size_t)s3 * F_IN + lane];
            acc += (a0 + a1) + (a2 + a3);
        }
        for (; j < d; ++j) acc += x[(size_t)sorted_src[rs + j] * F_IN + lane];
        float inv = 1.0f / fmaxf((float)d, 1.0f);
        as[wave][lane] = acc * inv;
        xs4[wave][lane] = x[(size_t)n * F_IN + lane];
    }
    __syncthreads();

    float a0 = b1[lane], a1 = b1[lane + 64];
    for (int i = 0; i < F_IN; ++i) {
        float av = as[wave][i], xv = xs4[wave][i];
        a0 += av * W1l[i * H + lane] + xv * W1r[i * H + lane];
        a1 += av * W1l[i * H + 64 + lane] + xv * W1r[i * H + 64 + lane];
    }
    int f0 = lane, f1 = lane + 64;
    float y0 = (a0 - m[f0]) * rsqrtf(v[f0] + EPSL) * g[f0] + bb[f0];
    float y1 = (a1 - m[f1]) * rsqrtf(v[f1] + EPSL) * g[f1] + bb[f1];
    h1b[(size_t)n * H + f0] = f2bf(fmaxf(y0, 0.f));
    h1b[(size_t)n * H + f1] = f2bf(fmaxf(y1, 0.f));
}

// ---------- fused agg2 + layer2 v4: bf16 gather into bf16 LDS + MFMA GEMM (K=256) ----------
__global__ __launch_bounds__(256) void k_agg2_layer2(
    const short* __restrict__ h1b, const int* __restrict__ rowstart,
    const int* __restrict__ cnt, const int* __restrict__ sorted_src,
    const int* __restrict__ perm,
    const short* __restrict__ W2t,  // [128][256] bf16: cols 0-127 = W2l^T, 128-255 = W2r^T
    const float* __restrict__ b2,
    const float* __restrict__ g, const float* __restrict__ bb,
    const float* __restrict__ m, const float* __restrict__ v,
    short* __restrict__ hb) {
    __shared__ short xs[32 * LDA2];  // row r: [0:128)=agg_mean bf16, [128:256)=root bf16
    __shared__ int nid[32];
    int t = threadIdx.x;
    int wave = t >> 6, lane = t & 63;
    int q4 = lane >> 4;   // which node of the group of 4
    int li = lane & 15;   // 16 lanes x int4 = full 256 B bf16 row
    int lr = lane & 15, lk = lane >> 4;
    int n0 = blockIdx.x * 32;

    // gather: quarter-wave per node, int4 (8 bf16) per lane
    for (int gq = 0; gq < 2; ++gq) {
        int r = wave * 8 + gq * 4 + q4;
        int n = perm[n0 + r];
        if (li == 0) nid[r] = n;
        int rs = rowstart[n];
        int d = cnt[n];
        float acc[8] = {0.f, 0.f, 0.f, 0.f, 0.f, 0.f, 0.f, 0.f};
        for (int j = 0; j < d; j += 4) {
            int rem = d - j;
            int4 v0 = *(const int4*)&h1b[(size_t)sorted_src[rs + j] * H + li * 8];
            int4 v1 = {0, 0, 0, 0}, v2 = {0, 0, 0, 0}, v3 = {0, 0, 0, 0};
            if (rem > 1) v1 = *(const int4*)&h1b[(size_t)sorted_src[rs + j + 1] * H + li * 8];
            if (rem > 2) v2 = *(const int4*)&h1b[(size_t)sorted_src[rs + j + 2] * H + li * 8];
            if (rem > 3) v3 = *(const int4*)&h1b[(size_t)sorted_src[rs + j + 3] * H + li * 8];
            acc8(acc, v0); acc8(acc, v1); acc8(acc, v2); acc8(acc, v3);
        }
        float inv = 1.f / fmaxf((float)d, 1.f);
        short packed[8];
#pragma unroll
        for (int q = 0; q < 8; ++q) packed[q] = f2bf(acc[q] * inv);
        *(int4*)&xs[r * LDA2 + 8 * li] = *(int4*)packed;
        // root: raw bf16 copy, no unpack
        int4 rv = *(const int4*)&h1b[(size_t)n * H + li * 8];
        *(int4*)&xs[r * LDA2 + 128 + 8 * li] = rv;
    }
    __syncthreads();

    // MFMA GEMM: C(32x128) = xs(32x256) @ W2t^T; wave w owns cols [32w, 32w+32)
    f32x4 acc2[2][2] = {};
    for (int ks = 0; ks < 8; ++ks) {
        bf16x8 b0 = *(const bf16x8*)&W2t[(32 * wave + lr) * 256 + 32 * ks + 8 * lk];
        bf16x8 b1 = *(const bf16x8*)&W2t[(32 * wave + 16 + lr) * 256 + 32 * ks + 8 * lk];
        bf16x8 a0 = *(bf16x8*)&xs[lr * LDA2 + 32 * ks + 8 * lk];
        bf16x8 a1 = *(bf16x8*)&xs[(16 + lr) * LDA2 + 32 * ks + 8 * lk];
        acc2[0][0] = __builtin_amdgcn_mfma_f32_16x16x32_bf16(a0, b0, acc2[0][0], 0, 0, 0);
        acc2[0][1] = __builtin_amdgcn_mfma_f32_16x16x32_bf16(a0, b1, acc2[0][1], 0, 0, 0);
        acc2[1][0] = __builtin_amdgcn_mfma_f32_16x16x32_bf16(a1, b0, acc2[1][0], 0, 0, 0);
        acc2[1][1] = __builtin_amdgcn_mfma_f32_16x16x32_bf16(a1, b1, acc2[1][1], 0, 0, 0);
    }
    // epilogue: C[row=16rr+4lk+j][col=32w+16cc+lr]
#pragma unroll
    for (int cc = 0; cc < 2; ++cc) {
        int c = 32 * wave + 16 * cc + lr;
        float bi = b2[c];
        float sc = rsqrtf(v[c] + EPSL) * g[c];
        float mm = m[c], be = bb[c];
#pragma unroll
        for (int rr = 0; rr < 2; ++rr)
#pragma unroll
            for (int j = 0; j < 4; ++j) {
                int row = 16 * rr + 4 * lk + j;
                float y = (acc2[rr][cc][j] + bi - mm) * sc + be;
                hb[(size_t)nid[row] * H + c] = f2bf(fmaxf(y, 0.f));
            }
    }
}

// ---------- heads via MFMA v3: wave-owns-columns, B in registers ----------
__global__ __launch_bounds__(256) void k_heads_mfma(
    const short* __restrict__ hb,
    const float* __restrict__ cntb1, const float* __restrict__ ch_b1,
    const short* __restrict__ W1t, const short* __restrict__ W2ft,
    const short* __restrict__ W3ft, const short* __restrict__ cntW1t,
    const short* __restrict__ cntW2ft,
    const float* __restrict__ b2f, const float* __restrict__ b3f,
    const float* __restrict__ cntb2f,
    float* __restrict__ out) {
    __shared__ short hs[64 * LDH];
    __shared__ short z1[64 * LDH];
    __shared__ short z2[64 * LDZ];

    int t = threadIdx.x;
    int lane = t & 63, w = t >> 6;
    int lr = lane & 15, lk = lane >> 4;
    int rh = w >> 1, ch = w & 1;
    int n0 = blockIdx.x * 64;

#pragma unroll
    for (int it = 0; it < 4; ++it) {
        int idx = t * 8 + it * 2048;
        int r = idx >> 7, c = idx & 127;
        int n = n0 + r;
        if (n > N_NODES - 1) n = N_NODES - 1;
        *(int4*)&hs[r * LDH + c] = *(const int4*)&hb[(size_t)n * 128 + c];
    }
    __syncthreads();

    // ===== count head G1: hs(64x128) @ cntW1t^T -> z2(64x64) =====
    {
        bf16x8 Bv[2][4];
#pragma unroll
        for (int cc = 0; cc < 2; ++cc)
#pragma unroll
            for (int ks = 0; ks < 4; ++ks)
                Bv[cc][ks] = *(const bf16x8*)&cntW1t[(32 * ch + 16 * cc + lr) * 128 + 32 * ks + 8 * lk];
        f32x4 acc[2][2] = {};
#pragma unroll
        for (int ks = 0; ks < 4; ++ks) {
            bf16x8 a0 = *(bf16x8*)&hs[(32 * rh + lr) * LDH + 32 * ks + 8 * lk];
            bf16x8 a1 = *(bf16x8*)&hs[(32 * rh + 16 + lr) * LDH + 32 * ks + 8 * lk];
#pragma unroll
            for (int cc = 0; cc < 2; ++cc) {
                acc[0][cc] = __builtin_amdgcn_mfma_f32_16x16x32_bf16(a0, Bv[cc][ks], acc[0][cc], 0, 0, 0);
                acc[1][cc] = __builtin_amdgcn_mfma_f32_16x16x32_bf16(a1, Bv[cc][ks], acc[1][cc], 0, 0, 0);
            }
        }
#pragma unroll
        for (int rr = 0; rr < 2; ++rr)
#pragma unroll
            for (int cc = 0; cc < 2; ++cc) {
                int c = 32 * ch + 16 * cc + lr;
                float bi = cntb1[c];
#pragma unroll
                for (int j = 0; j < 4; ++j) {
                    int r = 32 * rh + 16 * rr + 4 * lk + j;
                    z2[r * LDZ + c] = f2bf(fmaxf(acc[rr][cc][j] + bi, 0.f));
                }
            }
    }
    __syncthreads();
    // ===== count head G2: z2 @ cntW2ft^T -> out[:,0:6]; wave w rows [16w..) =====
    {
        f32x4 acc = {};
#pragma unroll
        for (int ks = 0; ks < 2; ++ks) {
            bf16x8 b = *(const bf16x8*)&cntW2ft[lr * 64 + 32 * ks + 8 * lk];
            bf16x8 a = *(bf16x8*)&z2[(16 * w + lr) * LDZ + 32 * ks + 8 * lk];
            acc = __builtin_amdgcn_mfma_f32_16x16x32_bf16(a, b, acc, 0, 0, 0);
        }
        if (lr < 6) {
            float bi = cntb2f[lr];
#pragma unroll
            for (int j = 0; j < 4; ++j) {
                int r = 16 * w + 4 * lk + j, n = n0 + r;
                if (n < N_NODES) out[(size_t)n * OUT_F + lr] = acc[j] + bi;
            }
        }
    }

    // ===== coord heads =====
    for (int k = 0; k < K_TYPES; ++k) {
        const short* W1k = W1t + k * 16384;
        {
            bf16x8 Bv[2][4];
#pragma unroll
            for (int cc = 0; cc < 2; ++cc)
#pragma unroll
                for (int ks = 0; ks < 4; ++ks)
                    Bv[cc][ks] = *(const bf16x8*)&W1k[(32 * w + 16 * cc + lr) * 128 + 32 * ks + 8 * lk];
            f32x4 acc[4][2] = {};
#pragma unroll
            for (int ks = 0; ks < 4; ++ks) {
                bf16x8 a0 = *(bf16x8*)&hs[(lr) * LDH + 32 * ks + 8 * lk];
                bf16x8 a1 = *(bf16x8*)&hs[(16 + lr) * LDH + 32 * ks + 8 * lk];
                bf16x8 a2 = *(bf16x8*)&hs[(32 + lr) * LDH + 32 * ks + 8 * lk];
                bf16x8 a3 = *(bf16x8*)&hs[(48 + lr) * LDH + 32 * ks + 8 * lk];
#pragma unroll
                for (int cc = 0; cc < 2; ++cc) {
                    acc[0][cc] = __builtin_amdgcn_mfma_f32_16x16x32_bf16(a0, Bv[cc][ks], acc[0][cc], 0, 0, 0);
                    acc[1][cc] = __builtin_amdgcn_mfma_f32_16x16x32_bf16(a1, Bv[cc][ks], acc[1][cc], 0, 0, 0);
                    acc[2][cc] = __builtin_amdgcn_mfma_f32_16x16x32_bf16(a2, Bv[cc][ks], acc[2][cc], 0, 0, 0);
                    acc[3][cc] = __builtin_amdgcn_mfma_f32_16x16x32_bf16(a3, Bv[cc][ks], acc[3][cc], 0, 0, 0);
                }
            }
#pragma unroll
            for (int rt = 0; rt < 4; ++rt)
#pragma unroll
                for (int cc = 0; cc < 2; ++cc) {
                    int c = 32 * w + 16 * cc + lr;
                    float bi = ch_b1[k * 128 + c];
#pragma unroll
                    for (int j = 0; j < 4; ++j) {
                        int r = 16 * rt + 4 * lk + j;
                        z1[r * LDH + c] = f2bf(fmaxf(acc[rt][cc][j] + bi, 0.f));
                    }
                }
        }
        __syncthreads();
        {
            const short* W2k = W2ft + k * 8192;
            bf16x8 Bv[2][4];
#pragma unroll
            for (int cc = 0; cc < 2; ++cc)
#pragma unroll
                for (int ks = 0; ks < 4; ++ks)
                    Bv[cc][ks] = *(const bf16x8*)&W2k[(32 * ch + 16 * cc + lr) * 128 + 32 * ks + 8 * lk];
            f32x4 acc[2][2] = {};
#pragma unroll
            for (int ks = 0; ks < 4; ++ks) {
                bf16x8 a0 = *(bf16x8*)&z1[(32 * rh + lr) * LDH + 32 * ks + 8 * lk];
                bf16x8 a1 = *(bf16x8*)&z1[(32 * rh + 16 + lr) * LDH + 32 * ks + 8 * lk];
#pragma unroll
                for (int cc = 0; cc < 2; ++cc) {
                    acc[0][cc] = __builtin_amdgcn_mfma_f32_16x16x32_bf16(a0, Bv[cc][ks], acc[0][cc], 0, 0, 0);
                    acc[1][cc] = __builtin_amdgcn_mfma_f32_16x16x32_bf16(a1, Bv[cc][ks], acc[1][cc], 0, 0, 0);
                }
            }
#pragma unroll
            for (int rr = 0; rr < 2; ++rr)
#pragma unroll
                for (int cc = 0; cc < 2; ++cc) {
                    int c = 32 * ch + 16 * cc + lr;
                    float bi = b2f[k * 64 + c];
#pragma unroll
                    for (int j = 0; j < 4; ++j) {
                        int r = 32 * rh + 16 * rr + 4 * lk + j;
                        z2[r * LDZ + c] = f2bf(fmaxf(acc[rr][cc][j] + bi, 0.f));
                    }
                }
        }
        __syncthreads();
        {
            const short* W3k = W3ft + k * 2048;
            bf16x8 Bv2[2];
#pragma unroll
            for (int ks = 0; ks < 2; ++ks)
                Bv2[ks] = *(const bf16x8*)&W3k[(16 * ch + lr) * 64 + 32 * ks + 8 * lk];
            f32x4 acc[2] = {};
#pragma unroll
            for (int ks = 0; ks < 2; ++ks) {
                bf16x8 a0 = *(bf16x8*)&z2[(32 * rh + lr) * LDZ + 32 * ks + 8 * lk];
                bf16x8 a1 = *(bf16x8*)&z2[(32 * rh + 16 + lr) * LDZ + 32 * ks + 8 * lk];
                acc[0] = __builtin_amdgcn_mfma_f32_16x16x32_bf16(a0, Bv2[ks], acc[0], 0, 0, 0);
                acc[1] = __builtin_amdgcn_mfma_f32_16x16x32_bf16(a1, Bv2[ks], acc[1], 0, 0, 0);
            }
            int c = 16 * ch + lr;
            if (c < 24) {
                float bi = b3f[k * 24 + c];
#pragma unroll
                for (int rr = 0; rr < 2; ++rr)
#pragma unroll
                    for (int j = 0; j < 4; ++j) {
                        int r = 32 * rh + 16 * rr + 4 * lk + j, n = n0 + r;
                        if (n < N_NODES)
                            out[(size_t)n * OUT_F + 6 + 24 * k + c] =
                                1.f / (1.f + expf(-(acc[rr][j] + bi)));
                    }
            }
        }
    }
}

extern "C" void kernel_launch(void* const* d_in, const int* in_sizes, int n_in,
                              void* d_out, int out_size, void* d_ws, size_t ws_size,
                              hipStream_t stream) {
    const float* x = (const float*)d_in[0];
    const int* ei = (const int*)d_in[1];
    const float* W1l = (const float*)d_in[2];
    const float* W1r = (const float*)d_in[3];
    const float* b1 = (const float*)d_in[4];
    const float* bn1_g = (const float*)d_in[5];
    const float* bn1_b = (const float*)d_in[6];
    const float* bn1_m = (const float*)d_in[7];
    const float* bn1_v = (const float*)d_in[8];
    const float* W2l = (const float*)d_in[9];
    const float* W2r = (const float*)d_in[10];
    const float* b2 = (const float*)d_in[11];
    const float* bn2_g = (const float*)d_in[12];
    const float* bn2_b = (const float*)d_in[13];
    const float* bn2_m = (const float*)d_in[14];
    const float* bn2_v = (const float*)d_in[15];
    const float* cnt_W1 = (const float*)d_in[16];
    const float* cnt_b1 = (const float*)d_in[17];
    const float* cnt_bn_g = (const float*)d_in[18];
    const float* cnt_bn_b = (const float*)d_in[19];
    const float* cnt_bn_m = (const float*)d_in[20];
    const float* cnt_bn_v = (const float*)d_in[21];
    const float* cnt_W2 = (const float*)d_in[22];
    const float* cnt_b2 = (const float*)d_in[23];
    const float* ch_W1 = (const float*)d_in[24];
    const float* ch_b1 = (const float*)d_in[25];
    const float* ch_bn1_g = (const float*)d_in[26];
    const float* ch_bn1_b = (const float*)d_in[27];
    const float* ch_bn1_m = (const float*)d_in[28];
    const float* ch_bn1_v = (const float*)d_in[29];
    const float* ch_W2 = (const float*)d_in[30];
    const float* ch_b2 = (const float*)d_in[31];
    const float* ch_bn2_g = (const float*)d_in[32];
    const float* ch_bn2_b = (const float*)d_in[33];
    const float* ch_bn2_m = (const float*)d_in[34];
    const float* ch_bn2_v = (const float*)d_in[35];
    const float* ch_W3 = (const float*)d_in[36];
    const float* ch_b3 = (const float*)d_in[37];

    float* out = (float*)d_out;

    int* cnt = (int*)d_ws;
    int* dbins = cnt + N_NODES;
    int* dcur = dbins + 64;
    int* rowstart = dcur + 64;
    int* cursor = rowstart + N_NODES;
    int* blocksums = cursor + N_NODES;
    int* perm = blocksums + 512;
    int* sorted_src = perm + N_NODES;
    short* h1b = (short*)(sorted_src + N_EDGES);
    short* hb = h1b + (size_t)N_NODES * H;
    short* W1t = hb + (size_t)N_NODES * H;
    short* W2ft = W1t + 98304;
    short* W3ft = W2ft + 49152;
    short* cntW1t = W3ft + 12288;
    short* cntW2ft = cntW1t + 8192;
    short* W2t = cntW2ft + 1024;
    float* b2f = (float*)(W2t + 32768);
    float* b3f = b2f + 384;
    float* cntb2f = b3f + 144;

    hipMemsetAsync(cnt, 0, (N_NODES + 64) * sizeof(int), stream);

    k_prep<<<791, 256, 0, stream>>>(ch_W1, ch_W2, ch_W3,
                                    ch_bn1_g, ch_bn1_b, ch_bn1_m, ch_bn1_v,
                                    ch_bn2_g, ch_bn2_b, ch_bn2_m, ch_bn2_v,
                                    cnt_W1, cnt_W2,
                                    cnt_bn_g, cnt_bn_b, cnt_bn_m, cnt_bn_v,
                                    ch_b2, ch_b3, cnt_b2, W2l, W2r,
                                    W1t, W2ft, W3ft, cntW1t, cntW2ft, W2t,
                                    b2f, b3f, cntb2f);

    k_hist<<<N_EDGES / 256, 256, 0, stream>>>(ei, cnt);
    k_scan1<<<SCAN_BLOCKS, 256, 0, stream>>>(cnt, rowstart, blocksums);
    k_scan2<<<1, 512, 0, stream>>>(blocksums);
    k_scan3<<<SCAN_BLOCKS, 256, 0, stream>>>(rowstart, blocksums, cursor);
    k_fill<<<N_EDGES / 256, 256, 0, stream>>>(ei, cursor, sorted_src);

    k_deghist<<<SCAN_BLOCKS, 256, 0, stream>>>(cnt, dbins);
    k_degscan<<<1, 64, 0, stream>>>(dbins, dcur);
    k_degscatter<<<SCAN_BLOCKS, 256, 0, stream>>>(cnt, dcur, perm);

    k_agg1_layer1<<<N_NODES / 4, 256, 0, stream>>>(x, rowstart, cnt, sorted_src, perm,
                                                   W1l, W1r, b1,
                                                   bn1_g, bn1_b, bn1_m, bn1_v, h1b);
    k_agg2_layer2<<<N_NODES / 32, 256, 0, stream>>>(h1b, rowstart, cnt, sorted_src, perm,
                                                    W2t, b2,
                                                    bn2_g, bn2_b, bn2_m, bn2_v, hb);
    k_heads_mfma<<<(N_NODES + 63) / 64, 256, 0, stream>>>(
        hb, cnt_b1, ch_b1, W1t, W2ft, W3ft, cntW1t, cntW2ft,
        b2f, b3f, cntb2f, out);
}